// Round 1
// baseline (2390.140 us; speedup 1.0000x reference)
//
#include <hip/hip_runtime.h>
#include <float.h>
#include <math.h>

// Problem constants (fixed by setup_inputs)
#define B_Q   2048
#define N_S   16384
#define DIM   512
#define C_CLS 17
#define K_TOP 8
#define TAU_F 10.0f
#define EPSF  1e-12f

// ---- workspace layout (in floats) ----
#define WS_PART   0            // 64 * 8704  per-block centroid partial sums
#define WS_PCNT   557056       // 64 * 32    per-block class counts
#define WS_CN     559104       // 8704       normalized centroids [C][D]
#define WS_TINV   567808       // N          2/max(||s||,eps)
#define WS_YY     584192       // N          sum(Yn^2)
#define WS_CLS    600576       // N          argmax class (int)
#define WS_P      616960       // N*C        softmax probs
#define WS_ZN     895488       // B*D        normalized queries
#define WS_XX     1944064      // B          sum(Xn^2)
#define WS_CANDS  1946112      // B*64       candidate scores
#define WS_CANDI  2077184      // B*64       candidate indices (int)
// total: 2,208,256 floats = ~8.8 MB

// ======================= centroid partial accumulation =======================
__global__ __launch_bounds__(256) void k_centroid_accum(
    const float* __restrict__ supports, const float* __restrict__ labels,
    float* __restrict__ part, float* __restrict__ pcnt)
{
    __shared__ float acc[C_CLS * DIM];   // 34,816 B
    __shared__ float lcnt[C_CLS];
    __shared__ int   lcls[256];
    const int tid = threadIdx.x;
    for (int i = tid; i < C_CLS * DIM; i += 256) acc[i] = 0.f;
    if (tid < C_CLS) lcnt[tid] = 0.f;

    const int n = blockIdx.x * 256 + tid;
    float best = labels[n * C_CLS + 0];
    int bc = 0;
    #pragma unroll
    for (int c = 1; c < C_CLS; ++c) {
        float v = labels[n * C_CLS + c];
        if (v > best) { best = v; bc = c; }
    }
    lcls[tid] = bc;
    __syncthreads();
    atomicAdd(&lcnt[bc], best);   // best == 1.0 (one-hot); LDS atomic

    const int d0 = tid, d1 = tid + 256;
    const int base = blockIdx.x * 256;
    for (int r = 0; r < 256; ++r) {
        const int c = lcls[r];
        const float* srow = supports + (size_t)(base + r) * DIM;
        acc[c * DIM + d0] += srow[d0];
        acc[c * DIM + d1] += srow[d1];
    }
    __syncthreads();
    float* pout = part + (size_t)blockIdx.x * (C_CLS * DIM);
    for (int i = tid; i < C_CLS * DIM; i += 256) pout[i] = acc[i];
    if (tid < C_CLS) pcnt[blockIdx.x * 32 + tid] = lcnt[tid];
}

// ======================= centroid finalize (normalize) =======================
__global__ __launch_bounds__(256) void k_centroid_fin(
    const float* __restrict__ part, const float* __restrict__ pcnt,
    float* __restrict__ cn)
{
    __shared__ float red[4];
    const int c = blockIdx.x, tid = threadIdx.x;
    float cntv = 0.f;
    for (int b = 0; b < 64; ++b) cntv += pcnt[b * 32 + c];
    const float denc = cntv + EPSF;
    float v0 = 0.f, v1 = 0.f;
    for (int b = 0; b < 64; ++b) {
        const float* pb = part + (size_t)b * (C_CLS * DIM) + c * DIM;
        v0 += pb[tid];
        v1 += pb[tid + 256];
    }
    v0 /= denc;
    v1 /= denc;
    float ss = v0 * v0 + v1 * v1;
    #pragma unroll
    for (int m = 1; m < 64; m <<= 1) ss += __shfl_xor(ss, m, 64);
    if ((tid & 63) == 0) red[tid >> 6] = ss;
    __syncthreads();
    const float tot = red[0] + red[1] + red[2] + red[3];
    const float den = fmaxf(sqrtf(tot), EPSF);
    cn[c * DIM + tid]       = v0 / den;
    cn[c * DIM + 256 + tid] = v1 / den;
}

// ============ per-support: norm, yy, temp_labels -> argmax + softmax ==========
__global__ __launch_bounds__(256) void k_support_stats(
    const float* __restrict__ supports, const float* __restrict__ cn,
    float* __restrict__ tinv, float* __restrict__ yy,
    int* __restrict__ cls, float* __restrict__ p)
{
    __shared__ float cnl[C_CLS * DIM];
    const int tid = threadIdx.x;
    for (int i = tid; i < C_CLS * DIM; i += 256) cnl[i] = cn[i];
    __syncthreads();

    const int w = tid >> 6, lane = tid & 63;
    const int n = blockIdx.x * 4 + w;
    const float* srow = supports + (size_t)n * DIM;

    float s[8];
    #pragma unroll
    for (int i = 0; i < 8; ++i) s[i] = srow[lane + 64 * i];
    float ss = 0.f;
    #pragma unroll
    for (int i = 0; i < 8; ++i) ss += s[i] * s[i];
    #pragma unroll
    for (int m = 1; m < 64; m <<= 1) ss += __shfl_xor(ss, m, 64);
    const float den = fmaxf(sqrtf(ss), EPSF);

    float yn[8];
    #pragma unroll
    for (int i = 0; i < 8; ++i) yn[i] = s[i] / den;
    float y2 = 0.f;
    #pragma unroll
    for (int i = 0; i < 8; ++i) y2 += yn[i] * yn[i];
    #pragma unroll
    for (int m = 1; m < 64; m <<= 1) y2 += __shfl_xor(y2, m, 64);

    float tl[C_CLS];
    #pragma unroll
    for (int c = 0; c < C_CLS; ++c) {
        float d = 0.f;
        #pragma unroll
        for (int i = 0; i < 8; ++i) d += yn[i] * cnl[c * DIM + lane + 64 * i];
        #pragma unroll
        for (int m = 1; m < 64; m <<= 1) d += __shfl_xor(d, m, 64);
        tl[c] = TAU_F * d;
    }
    float mx = tl[0];
    int am = 0;
    #pragma unroll
    for (int c = 1; c < C_CLS; ++c)
        if (tl[c] > mx) { mx = tl[c]; am = c; }
    float e[C_CLS];
    float sum = 0.f;
    #pragma unroll
    for (int c = 0; c < C_CLS; ++c) { e[c] = expf(tl[c] - mx); sum += e[c]; }

    if (lane == 0) {
        tinv[n] = 2.0f / den;
        yy[n]   = y2;
        cls[n]  = am;
        #pragma unroll
        for (int c = 0; c < C_CLS; ++c) p[n * C_CLS + c] = e[c] / sum;
    }
}

// ======================= query normalize =======================
__global__ __launch_bounds__(256) void k_query_norm(
    const float* __restrict__ z, float* __restrict__ zn, float* __restrict__ xx)
{
    const int tid = threadIdx.x, w = tid >> 6, lane = tid & 63;
    const int q = blockIdx.x * 4 + w;
    const float* zr = z + (size_t)q * DIM;
    float s[8];
    float ss = 0.f;
    #pragma unroll
    for (int i = 0; i < 8; ++i) { s[i] = zr[lane + 64 * i]; ss += s[i] * s[i]; }
    #pragma unroll
    for (int m = 1; m < 64; m <<= 1) ss += __shfl_xor(ss, m, 64);
    const float den = fmaxf(sqrtf(ss), EPSF);
    float x2 = 0.f;
    #pragma unroll
    for (int i = 0; i < 8; ++i) {
        float v = s[i] / den;
        zn[(size_t)q * DIM + lane + 64 * i] = v;
        x2 += v * v;
    }
    #pragma unroll
    for (int m = 1; m < 64; m <<= 1) x2 += __shfl_xor(x2, m, 64);
    if (lane == 0) xx[q] = x2;
}

// ======================= big kernel: scores + per-slice top-8 =======================
#define SA 68   // padded row stride in floats (bank-decorrelated, 16B aligned)

__global__ __launch_bounds__(256) void k_score_topk(
    const float* __restrict__ supports, const float* __restrict__ zn,
    const float* __restrict__ tinv, const float* __restrict__ yy,
    const float* __restrict__ xx,
    float* __restrict__ cand_s, int* __restrict__ cand_i)
{
    __shared__ __align__(16) float As[32 * SA];    //  8.7 KB
    __shared__ __align__(16) float Bs[128 * SA];   // 34.8 KB
    const int tid   = threadIdx.x;
    const int qtile = blockIdx.x & 63;
    const int slice = blockIdx.x >> 6;
    const int q0    = qtile * 32;
    const int sbase = slice * 2048;
    const int qgrp  = tid >> 5;   // 0..7
    const int sgrp  = tid & 31;   // 0..31

    float ts[4][8]; int ti[4][8];
    float tmn[4]; int tmni[4]; int tmns[4];
    #pragma unroll
    for (int i = 0; i < 4; ++i) {
        #pragma unroll
        for (int r = 0; r < 8; ++r) { ts[i][r] = -FLT_MAX; ti[i][r] = 0x7fffffff; }
        tmn[i] = -FLT_MAX; tmni[i] = 0x7fffffff; tmns[i] = 0;
    }
    float xq[4];
    #pragma unroll
    for (int i = 0; i < 4; ++i) xq[i] = xx[q0 + i * 8 + qgrp];

    const int a_r = tid >> 3, a_k = (tid & 7) * 4;
    const int b_r = tid >> 4, b_k = (tid & 15) * 4;

    for (int chunk = 0; chunk < 16; ++chunk) {
        float acc[4][4];
        #pragma unroll
        for (int i = 0; i < 4; ++i)
            #pragma unroll
            for (int j = 0; j < 4; ++j) acc[i][j] = 0.f;

        const float* supC = supports + (size_t)(sbase + chunk * 128) * DIM;
        for (int ks = 0; ks < 8; ++ks) {
            __syncthreads();
            {   // stage A: 32 x 64
                const float* src = zn + (size_t)(q0 + a_r) * DIM + ks * 64 + a_k;
                float4 v0 = *(const float4*)src;
                float4 v1 = *(const float4*)(src + 32);
                *(float4*)(As + a_r * SA + a_k)      = v0;
                *(float4*)(As + a_r * SA + a_k + 32) = v1;
            }
            #pragma unroll
            for (int m = 0; m < 8; ++m) {   // stage B: 128 x 64
                const int r = b_r + m * 16;
                float4 v = *(const float4*)(supC + (size_t)r * DIM + ks * 64 + b_k);
                *(float4*)(Bs + r * SA + b_k) = v;
            }
            __syncthreads();
            #pragma unroll
            for (int kk = 0; kk < 64; kk += 4) {
                float4 av[4], bv[4];
                #pragma unroll
                for (int i = 0; i < 4; ++i)
                    av[i] = *(const float4*)(As + (i * 8 + qgrp) * SA + kk);
                #pragma unroll
                for (int j = 0; j < 4; ++j)
                    bv[j] = *(const float4*)(Bs + (j * 32 + sgrp) * SA + kk);
                #pragma unroll
                for (int i = 0; i < 4; ++i)
                    #pragma unroll
                    for (int j = 0; j < 4; ++j)
                        acc[i][j] += av[i].x * bv[j].x + av[i].y * bv[j].y +
                                     av[i].z * bv[j].z + av[i].w * bv[j].w;
            }
        }
        // scores + top-8 update (rank on W = exp(-dist), ties -> lower index)
        #pragma unroll
        for (int j = 0; j < 4; ++j) {
            const int sj = sbase + chunk * 128 + j * 32 + sgrp;
            const float tv = tinv[sj], yv = yy[sj];
            #pragma unroll
            for (int i = 0; i < 4; ++i) {
                const float dist = xq[i] + yv - acc[i][j] * tv;
                const float sc = expf(-dist);
                const bool better = (sc > tmn[i]) || ((sc == tmn[i]) && (sj < tmni[i]));
                if (better) {
                    #pragma unroll
                    for (int r = 0; r < 8; ++r)
                        if (r == tmns[i]) { ts[i][r] = sc; ti[i][r] = sj; }
                    float ms = ts[i][0]; int mi = ti[i][0]; int msl = 0;
                    #pragma unroll
                    for (int r = 1; r < 8; ++r) {
                        const bool wrs = (ts[i][r] < ms) ||
                                         ((ts[i][r] == ms) && (ti[i][r] > mi));
                        if (wrs) { ms = ts[i][r]; mi = ti[i][r]; msl = r; }
                    }
                    tmn[i] = ms; tmni[i] = mi; tmns[i] = msl;
                }
            }
        }
    }

    // block-level merge: 32 sgrp-threads' top-8 -> per-(query,slice) top-8
    float* msch = Bs;          // >= 2048 floats
    int*   mich = (int*)As;    // >= 2048 ints
    #pragma unroll
    for (int i = 0; i < 4; ++i) {
        __syncthreads();
        #pragma unroll
        for (int r = 0; r < 8; ++r) {
            msch[tid * 8 + r] = ts[i][r];
            mich[tid * 8 + r] = ti[i][r];
        }
        __syncthreads();
        if (tid < 8) {
            float bs[8]; int bi[8];
            #pragma unroll
            for (int r = 0; r < 8; ++r) { bs[r] = -FLT_MAX; bi[r] = 0x7fffffff; }
            float mn = -FLT_MAX; int mni = 0x7fffffff; int mns = 0;
            for (int t = 0; t < 32; ++t) {
                const int off = (tid * 32 + t) * 8;
                #pragma unroll
                for (int r = 0; r < 8; ++r) {
                    const float sc = msch[off + r];
                    const int   sj = mich[off + r];
                    const bool better = (sc > mn) || ((sc == mn) && (sj < mni));
                    if (better) {
                        #pragma unroll
                        for (int u = 0; u < 8; ++u)
                            if (u == mns) { bs[u] = sc; bi[u] = sj; }
                        float ms = bs[0]; int mi = bi[0]; int msl = 0;
                        #pragma unroll
                        for (int u = 1; u < 8; ++u) {
                            const bool wrs = (bs[u] < ms) ||
                                             ((bs[u] == ms) && (bi[u] > mi));
                            if (wrs) { ms = bs[u]; mi = bi[u]; msl = u; }
                        }
                        mn = ms; mni = mi; mns = msl;
                    }
                }
            }
            const int q = q0 + i * 8 + tid;
            #pragma unroll
            for (int r = 0; r < 8; ++r) {
                cand_s[q * 64 + slice * 8 + r] = bs[r];
                cand_i[q * 64 + slice * 8 + r] = bi[r];
            }
        }
    }
}

// ======================= final merge + outputs + logits =======================
__global__ __launch_bounds__(256) void k_merge_out(
    const float* __restrict__ cand_s, const int* __restrict__ cand_i,
    const int* __restrict__ cls, const float* __restrict__ p,
    const float* __restrict__ zn, const float* __restrict__ cn,
    float* __restrict__ out)
{
    const int tid = threadIdx.x, w = tid >> 6, lane = tid & 63;
    const int q = blockIdx.x * 4 + w;

    float cs = cand_s[q * 64 + lane];
    int   ci = cand_i[q * 64 + lane];
    float tcnt = 0.f, osum = 0.f;
    #pragma unroll
    for (int r = 0; r < K_TOP; ++r) {
        float bsv = cs; int biv = ci;
        #pragma unroll
        for (int m = 1; m < 64; m <<= 1) {
            const float osc = __shfl_xor(bsv, m, 64);
            const int   oic = __shfl_xor(biv, m, 64);
            const bool take = (osc > bsv) || ((osc == bsv) && (oic < biv));
            if (take) { bsv = osc; biv = oic; }
        }
        if (ci == biv) cs = -FLT_MAX;   // candidate indices are unique
        const int cw = cls[biv];
        if (lane < C_CLS) {
            osum += p[biv * C_CLS + lane];
            tcnt += (cw == lane) ? 1.0f : 0.f;
        }
    }
    float tt = tcnt, ot = osum;
    #pragma unroll
    for (int m = 1; m < 64; m <<= 1) {
        tt += __shfl_xor(tt, m, 64);
        ot += __shfl_xor(ot, m, 64);
    }
    if (lane < C_CLS) {
        out[(size_t)B_Q * C_CLS + q * C_CLS + lane]     = tcnt / (tt + EPSF);
        out[(size_t)2 * B_Q * C_CLS + q * C_CLS + lane] = osum / (ot + EPSF);
    }

    // logits = TAU * Xn_q . cn_c
    const float* zr = zn + (size_t)q * DIM;
    float zv[8];
    #pragma unroll
    for (int i = 0; i < 8; ++i) zv[i] = zr[lane + 64 * i];
    #pragma unroll
    for (int c = 0; c < C_CLS; ++c) {
        float d = 0.f;
        #pragma unroll
        for (int i = 0; i < 8; ++i) d += zv[i] * cn[c * DIM + lane + 64 * i];
        #pragma unroll
        for (int m = 1; m < 64; m <<= 1) d += __shfl_xor(d, m, 64);
        if (lane == 0) out[q * C_CLS + c] = TAU_F * d;
    }
}

// ======================= launcher =======================
extern "C" void kernel_launch(void* const* d_in, const int* in_sizes, int n_in,
                              void* d_out, int out_size, void* d_ws, size_t ws_size,
                              hipStream_t stream)
{
    const float* z        = (const float*)d_in[0];
    const float* supports = (const float*)d_in[1];
    const float* labels   = (const float*)d_in[2];
    float* ws  = (float*)d_ws;
    float* out = (float*)d_out;

    float* part   = ws + WS_PART;
    float* pcnt   = ws + WS_PCNT;
    float* cn     = ws + WS_CN;
    float* tinv   = ws + WS_TINV;
    float* yyv    = ws + WS_YY;
    int*   cls    = (int*)(ws + WS_CLS);
    float* p      = ws + WS_P;
    float* zn     = ws + WS_ZN;
    float* xx     = ws + WS_XX;
    float* cand_s = ws + WS_CANDS;
    int*   cand_i = (int*)(ws + WS_CANDI);

    hipLaunchKernelGGL(k_centroid_accum, dim3(64), dim3(256), 0, stream,
                       supports, labels, part, pcnt);
    hipLaunchKernelGGL(k_centroid_fin, dim3(17), dim3(256), 0, stream,
                       part, pcnt, cn);
    hipLaunchKernelGGL(k_support_stats, dim3(N_S / 4), dim3(256), 0, stream,
                       supports, cn, tinv, yyv, cls, p);
    hipLaunchKernelGGL(k_query_norm, dim3(B_Q / 4), dim3(256), 0, stream,
                       z, zn, xx);
    hipLaunchKernelGGL(k_score_topk, dim3(512), dim3(256), 0, stream,
                       supports, zn, tinv, yyv, xx, cand_s, cand_i);
    hipLaunchKernelGGL(k_merge_out, dim3(B_Q / 4), dim3(256), 0, stream,
                       cand_s, cand_i, cls, p, zn, cn, out);
}

// Round 2
// 578.541 us; speedup vs baseline: 4.1313x; 4.1313x over previous
//
#include <hip/hip_runtime.h>
#include <float.h>
#include <math.h>

// Problem constants (fixed by setup_inputs)
#define B_Q   2048
#define N_S   16384
#define DIM   512
#define C_CLS 17
#define K_TOP 8
#define TAU_F 10.0f
#define EPSF  1e-12f

typedef _Float16 f16x8 __attribute__((ext_vector_type(8)));
typedef float    f32x16 __attribute__((ext_vector_type(16)));

#define GLDS(gp, lp) __builtin_amdgcn_global_load_lds( \
    (const __attribute__((address_space(1))) void*)(gp), \
    (__attribute__((address_space(3))) void*)(lp), 16, 0, 0)

// ---- workspace layout (in floats) ----
#define WS_PART   0            // 64 * 8704
#define WS_PCNT   557056       // 64 * 32
#define WS_CN     559104       // 17*512
#define WS_YY     567808       // N
#define WS_CLS    584192       // N (int)
#define WS_P      600576       // N*17
#define WS_ZN     879104       // B*D fp32
#define WS_XX     1927680      // B
#define WS_CANDS  1929728      // B*1024
#define WS_CANDI  4026880      // B*1024 (int)
#define WS_ZNH    6124032      // B*D f16   (524288 floats)
#define WS_ZNL    6648320      // B*D f16
#define WS_SUPH   7172608      // N*D f16   (4194304 floats)
#define WS_SUPL   11366912     // N*D f16
// total 15,561,216 floats = 62.2 MB

// ======================= centroid partial accumulation =======================
__global__ __launch_bounds__(256) void k_centroid_accum(
    const float* __restrict__ supports, const float* __restrict__ labels,
    float* __restrict__ part, float* __restrict__ pcnt)
{
    __shared__ float acc[C_CLS * DIM];
    __shared__ float lcnt[C_CLS];
    __shared__ int   lcls[256];
    const int tid = threadIdx.x;
    for (int i = tid; i < C_CLS * DIM; i += 256) acc[i] = 0.f;
    if (tid < C_CLS) lcnt[tid] = 0.f;

    const int n = blockIdx.x * 256 + tid;
    float best = labels[n * C_CLS + 0];
    int bc = 0;
    #pragma unroll
    for (int c = 1; c < C_CLS; ++c) {
        float v = labels[n * C_CLS + c];
        if (v > best) { best = v; bc = c; }
    }
    lcls[tid] = bc;
    __syncthreads();
    atomicAdd(&lcnt[bc], best);

    const int d0 = tid, d1 = tid + 256;
    const int base = blockIdx.x * 256;
    for (int r = 0; r < 256; ++r) {
        const int c = lcls[r];
        const float* srow = supports + (size_t)(base + r) * DIM;
        acc[c * DIM + d0] += srow[d0];
        acc[c * DIM + d1] += srow[d1];
    }
    __syncthreads();
    float* pout = part + (size_t)blockIdx.x * (C_CLS * DIM);
    for (int i = tid; i < C_CLS * DIM; i += 256) pout[i] = acc[i];
    if (tid < C_CLS) pcnt[blockIdx.x * 32 + tid] = lcnt[tid];
}

// ======================= centroid finalize (normalize) =======================
__global__ __launch_bounds__(256) void k_centroid_fin(
    const float* __restrict__ part, const float* __restrict__ pcnt,
    float* __restrict__ cn)
{
    __shared__ float red[4];
    const int c = blockIdx.x, tid = threadIdx.x;
    float cntv = 0.f;
    for (int b = 0; b < 64; ++b) cntv += pcnt[b * 32 + c];
    const float denc = cntv + EPSF;
    float v0 = 0.f, v1 = 0.f;
    for (int b = 0; b < 64; ++b) {
        const float* pb = part + (size_t)b * (C_CLS * DIM) + c * DIM;
        v0 += pb[tid];
        v1 += pb[tid + 256];
    }
    v0 /= denc;
    v1 /= denc;
    float ss = v0 * v0 + v1 * v1;
    #pragma unroll
    for (int m = 1; m < 64; m <<= 1) ss += __shfl_xor(ss, m, 64);
    if ((tid & 63) == 0) red[tid >> 6] = ss;
    __syncthreads();
    const float tot = red[0] + red[1] + red[2] + red[3];
    const float den = fmaxf(sqrtf(tot), EPSF);
    cn[c * DIM + tid]       = v0 / den;
    cn[c * DIM + 256 + tid] = v1 / den;
}

// ==== per-support: norm -> f16 hi/lo, yy, temp_labels -> argmax + softmax ====
__global__ __launch_bounds__(256) void k_support_stats(
    const float* __restrict__ supports, const float* __restrict__ cn,
    float* __restrict__ yy, int* __restrict__ cls, float* __restrict__ p,
    _Float16* __restrict__ suph, _Float16* __restrict__ supl)
{
    __shared__ float cnl[C_CLS * DIM];
    const int tid = threadIdx.x;
    for (int i = tid; i < C_CLS * DIM; i += 256) cnl[i] = cn[i];
    __syncthreads();

    const int w = tid >> 6, lane = tid & 63;
    const int n = blockIdx.x * 4 + w;
    const float* srow = supports + (size_t)n * DIM;

    float s[8];
    #pragma unroll
    for (int i = 0; i < 8; ++i) s[i] = srow[lane + 64 * i];
    float ss = 0.f;
    #pragma unroll
    for (int i = 0; i < 8; ++i) ss += s[i] * s[i];
    #pragma unroll
    for (int m = 1; m < 64; m <<= 1) ss += __shfl_xor(ss, m, 64);
    const float den = fmaxf(sqrtf(ss), EPSF);

    float yn[8];
    #pragma unroll
    for (int i = 0; i < 8; ++i) yn[i] = s[i] / den;
    float y2 = 0.f;
    #pragma unroll
    for (int i = 0; i < 8; ++i) y2 += yn[i] * yn[i];
    #pragma unroll
    for (int m = 1; m < 64; m <<= 1) y2 += __shfl_xor(y2, m, 64);

    // split to f16 hi/lo
    #pragma unroll
    for (int i = 0; i < 8; ++i) {
        const _Float16 hi = (_Float16)yn[i];
        suph[(size_t)n * DIM + lane + 64 * i] = hi;
        supl[(size_t)n * DIM + lane + 64 * i] = (_Float16)(yn[i] - (float)hi);
    }

    float tl[C_CLS];
    #pragma unroll
    for (int c = 0; c < C_CLS; ++c) {
        float d = 0.f;
        #pragma unroll
        for (int i = 0; i < 8; ++i) d += yn[i] * cnl[c * DIM + lane + 64 * i];
        #pragma unroll
        for (int m = 1; m < 64; m <<= 1) d += __shfl_xor(d, m, 64);
        tl[c] = TAU_F * d;
    }
    float mx = tl[0];
    int am = 0;
    #pragma unroll
    for (int c = 1; c < C_CLS; ++c)
        if (tl[c] > mx) { mx = tl[c]; am = c; }
    float e[C_CLS];
    float sum = 0.f;
    #pragma unroll
    for (int c = 0; c < C_CLS; ++c) { e[c] = expf(tl[c] - mx); sum += e[c]; }

    if (lane == 0) {
        yy[n]  = y2;
        cls[n] = am;
        #pragma unroll
        for (int c = 0; c < C_CLS; ++c) p[n * C_CLS + c] = e[c] / sum;
    }
}

// ======================= query normalize + f16 split =======================
__global__ __launch_bounds__(256) void k_query_norm(
    const float* __restrict__ z, float* __restrict__ zn, float* __restrict__ xx,
    _Float16* __restrict__ znh, _Float16* __restrict__ znl)
{
    const int tid = threadIdx.x, w = tid >> 6, lane = tid & 63;
    const int q = blockIdx.x * 4 + w;
    const float* zr = z + (size_t)q * DIM;
    float s[8];
    float ss = 0.f;
    #pragma unroll
    for (int i = 0; i < 8; ++i) { s[i] = zr[lane + 64 * i]; ss += s[i] * s[i]; }
    #pragma unroll
    for (int m = 1; m < 64; m <<= 1) ss += __shfl_xor(ss, m, 64);
    const float den = fmaxf(sqrtf(ss), EPSF);
    float x2 = 0.f;
    #pragma unroll
    for (int i = 0; i < 8; ++i) {
        const float v = s[i] / den;
        zn[(size_t)q * DIM + lane + 64 * i] = v;
        const _Float16 hi = (_Float16)v;
        znh[(size_t)q * DIM + lane + 64 * i] = hi;
        znl[(size_t)q * DIM + lane + 64 * i] = (_Float16)(v - (float)hi);
        x2 += v * v;
    }
    #pragma unroll
    for (int m = 1; m < 64; m <<= 1) x2 += __shfl_xor(x2, m, 64);
    if (lane == 0) xx[q] = x2;
}

// ============ MFMA split-f16 score GEMM + fused per-range top-8 ============
// Block tile 128(q) x 256(s), BK=32. 4 waves, each 64x128 (2x4 of 32x32).
// LDS halves: Ah[4g][128r]x8, Al, Bh[4g][256r]x8, Bl  => 48 KB, reused as
// per-wave 12KB scratch in the epilogue.
__global__ __launch_bounds__(256, 2) void k_score_mfma(
    const _Float16* __restrict__ znh, const _Float16* __restrict__ znl,
    const _Float16* __restrict__ suph, const _Float16* __restrict__ supl,
    const float* __restrict__ yy, const float* __restrict__ xx,
    float* __restrict__ cand_s, int* __restrict__ cand_i)
{
    __shared__ __align__(16) _Float16 lds[24576];   // 48 KB
    _Float16* Ah = lds;
    _Float16* Al = lds + 4096;
    _Float16* Bh = lds + 8192;
    _Float16* Bl = lds + 16384;

    const int tid = threadIdx.x;
    const int w = tid >> 6, l = tid & 63;
    const int h = l >> 5, ln = l & 31;
    const int bm = blockIdx.x & 15;
    const int bn = blockIdx.x >> 4;
    const int q0 = bm * 128, s0 = bn * 256;
    const int wm = w & 1, wn = w >> 1;

    f32x16 acc[2][4];
    #pragma unroll
    for (int t = 0; t < 2; ++t)
        #pragma unroll
        for (int u = 0; u < 4; ++u)
            #pragma unroll
            for (int e = 0; e < 16; ++e) acc[t][u][e] = 0.f;

    for (int chunk = 0; chunk < 16; ++chunk) {
        const int k0 = chunk * 32;
        __syncthreads();   // previous chunk's frag reads complete
        #pragma unroll
        for (int ii = 0; ii < 12; ++ii) {
            const int t = ii * 4 + w;   // wave-uniform 0..47
            if (t < 8) {
                const int gg = t >> 1, r0 = (t & 1) * 64;
                GLDS(znh + (size_t)(q0 + r0 + l) * DIM + k0 + gg * 8,
                     Ah + (gg * 128 + r0) * 8);
            } else if (t < 16) {
                const int t1 = t - 8, gg = t1 >> 1, r0 = (t1 & 1) * 64;
                GLDS(znl + (size_t)(q0 + r0 + l) * DIM + k0 + gg * 8,
                     Al + (gg * 128 + r0) * 8);
            } else if (t < 32) {
                const int t1 = t - 16, gg = t1 >> 2, r0 = (t1 & 3) * 64;
                GLDS(suph + (size_t)(s0 + r0 + l) * DIM + k0 + gg * 8,
                     Bh + (gg * 256 + r0) * 8);
            } else {
                const int t1 = t - 32, gg = t1 >> 2, r0 = (t1 & 3) * 64;
                GLDS(supl + (size_t)(s0 + r0 + l) * DIM + k0 + gg * 8,
                     Bl + (gg * 256 + r0) * 8);
            }
        }
        __syncthreads();   // staging visible (barrier drains vmcnt)

        #pragma unroll
        for (int kk = 0; kk < 2; ++kk) {
            const int g8 = kk * 2 + h;
            f16x8 ah[2], al[2], bh[4], bl[4];
            #pragma unroll
            for (int t = 0; t < 2; ++t) {
                ah[t] = *(const f16x8*)(Ah + (size_t)(g8 * 128 + wm * 64 + t * 32 + ln) * 8);
                al[t] = *(const f16x8*)(Al + (size_t)(g8 * 128 + wm * 64 + t * 32 + ln) * 8);
            }
            #pragma unroll
            for (int u = 0; u < 4; ++u) {
                bh[u] = *(const f16x8*)(Bh + (size_t)(g8 * 256 + wn * 128 + u * 32 + ln) * 8);
                bl[u] = *(const f16x8*)(Bl + (size_t)(g8 * 256 + wn * 128 + u * 32 + ln) * 8);
            }
            #pragma unroll
            for (int t = 0; t < 2; ++t)
                #pragma unroll
                for (int u = 0; u < 4; ++u) {
                    acc[t][u] = __builtin_amdgcn_mfma_f32_32x32x16_f16(ah[t], bh[u], acc[t][u], 0, 0, 0);
                    acc[t][u] = __builtin_amdgcn_mfma_f32_32x32x16_f16(ah[t], bl[u], acc[t][u], 0, 0, 0);
                    acc[t][u] = __builtin_amdgcn_mfma_f32_32x32x16_f16(al[t], bh[u], acc[t][u], 0, 0, 0);
                }
        }
    }

    // ---------------- epilogue: dist -> exp -> top-8 per (q, 128-col range) ----
    float* sw = ((float*)lds) + w * 3072;   // 12 KB per-wave scratch
    const int row16 = l & 15, seg = l >> 4;
    const int range = bn * 2 + wn;

    #pragma unroll
    for (int p = 0; p < 4; ++p) {
        const int t = p >> 1, rb = (p & 1) * 8;
        __syncthreads();   // prior pass merge reads done / K-loop reads done
        #pragma unroll
        for (int q = 0; q < 8; ++q) {
            const int lr = (q & 3) + 8 * (q >> 2) + 4 * h;
            #pragma unroll
            for (int u = 0; u < 4; ++u)
                sw[lr * 129 + u * 32 + ln] = acc[t][u][rb + q];
        }
        __syncthreads();

        float ts[8]; int ti[8];
        float tmn = -FLT_MAX; int tmni = 0x7fffffff; int tmns = 0;
        #pragma unroll
        for (int r = 0; r < 8; ++r) { ts[r] = -FLT_MAX; ti[r] = 0x7fffffff; }
        const int qg = q0 + wm * 64 + p * 16 + row16;
        const float xq = xx[qg];
        for (int j = 0; j < 32; ++j) {
            const int cc = seg * 32 + ((j + seg * 8) & 31);
            const float cv = sw[row16 * 129 + cc];
            const int sg = s0 + wn * 128 + cc;
            const float dist = xq + yy[sg] - 2.0f * cv;
            const float sc = expf(-dist);
            const bool better = (sc > tmn) || ((sc == tmn) && (sg < tmni));
            if (better) {
                #pragma unroll
                for (int r = 0; r < 8; ++r)
                    if (r == tmns) { ts[r] = sc; ti[r] = sg; }
                float ms = ts[0]; int mi = ti[0]; int msl = 0;
                #pragma unroll
                for (int r = 1; r < 8; ++r) {
                    const bool wrs = (ts[r] < ms) || ((ts[r] == ms) && (ti[r] > mi));
                    if (wrs) { ms = ts[r]; mi = ti[r]; msl = r; }
                }
                tmn = ms; tmni = mi; tmns = msl;
            }
        }
        __syncthreads();
        #pragma unroll
        for (int r = 0; r < 8; ++r) {
            sw[l * 17 + r] = ts[r];
            ((int*)sw)[l * 17 + 8 + r] = ti[r];
        }
        __syncthreads();
        if (l < 16) {
            float bs[8]; int bi[8];
            float mn = -FLT_MAX; int mni = 0x7fffffff; int mns = 0;
            #pragma unroll
            for (int r = 0; r < 8; ++r) { bs[r] = -FLT_MAX; bi[r] = 0x7fffffff; }
            for (int k = 0; k < 4; ++k) {
                const int off = (l + 16 * k) * 17;
                #pragma unroll
                for (int r = 0; r < 8; ++r) {
                    const float sc = sw[off + r];
                    const int   sj = ((int*)sw)[off + 8 + r];
                    const bool better = (sc > mn) || ((sc == mn) && (sj < mni));
                    if (better) {
                        #pragma unroll
                        for (int u = 0; u < 8; ++u)
                            if (u == mns) { bs[u] = sc; bi[u] = sj; }
                        float ms = bs[0]; int mi = bi[0]; int msl = 0;
                        #pragma unroll
                        for (int u = 1; u < 8; ++u) {
                            const bool wrs = (bs[u] < ms) || ((bs[u] == ms) && (bi[u] > mi));
                            if (wrs) { ms = bs[u]; mi = bi[u]; msl = u; }
                        }
                        mn = ms; mni = mi; mns = msl;
                    }
                }
            }
            #pragma unroll
            for (int r = 0; r < 8; ++r) {
                cand_s[(size_t)qg * 1024 + range * 8 + r] = bs[r];
                cand_i[(size_t)qg * 1024 + range * 8 + r] = bi[r];
            }
        }
    }
}

// ======================= final merge + outputs + logits =======================
__global__ __launch_bounds__(256) void k_merge_out(
    const float* __restrict__ cand_s, const int* __restrict__ cand_i,
    const int* __restrict__ cls, const float* __restrict__ p,
    const float* __restrict__ zn, const float* __restrict__ cn,
    float* __restrict__ out)
{
    const int tid = threadIdx.x, w = tid >> 6, lane = tid & 63;
    const int q = blockIdx.x * 4 + w;

    // local top-8 over this lane's 16 of the 1024 candidates
    float ts[8]; int ti[8];
    #pragma unroll
    for (int r = 0; r < 8; ++r) { ts[r] = -FLT_MAX; ti[r] = 0x7fffffff; }
    for (int j = 0; j < 16; ++j) {
        const float sc = cand_s[(size_t)q * 1024 + j * 64 + lane];
        const int   si = cand_i[(size_t)q * 1024 + j * 64 + lane];
        float mn = ts[0]; int mni = ti[0]; int slot = 0;
        #pragma unroll
        for (int r = 1; r < 8; ++r) {
            const bool wrs = (ts[r] < mn) || ((ts[r] == mn) && (ti[r] > mni));
            if (wrs) { mn = ts[r]; mni = ti[r]; slot = r; }
        }
        const bool better = (sc > mn) || ((sc == mn) && (si < mni));
        if (better) {
            #pragma unroll
            for (int r = 0; r < 8; ++r)
                if (r == slot) { ts[r] = sc; ti[r] = si; }
        }
    }

    float tcnt = 0.f, osum = 0.f;
    #pragma unroll
    for (int r = 0; r < K_TOP; ++r) {
        float mv = ts[0]; int mi = ti[0]; int ms = 0;
        #pragma unroll
        for (int u = 1; u < 8; ++u) {
            const bool b = (ts[u] > mv) || ((ts[u] == mv) && (ti[u] < mi));
            if (b) { mv = ts[u]; mi = ti[u]; ms = u; }
        }
        float bv = mv; int bi = mi;
        #pragma unroll
        for (int m = 1; m < 64; m <<= 1) {
            const float ov = __shfl_xor(bv, m, 64);
            const int   oi = __shfl_xor(bi, m, 64);
            const bool take = (ov > bv) || ((ov == bv) && (oi < bi));
            if (take) { bv = ov; bi = oi; }
        }
        if (mv == bv && mi == bi) {
            #pragma unroll
            for (int u = 0; u < 8; ++u)
                if (u == ms) { ts[u] = -FLT_MAX; ti[u] = 0x7fffffff; }
        }
        const int cw = cls[bi];
        if (lane < C_CLS) {
            osum += p[bi * C_CLS + lane];
            tcnt += (cw == lane) ? 1.0f : 0.f;
        }
    }
    float tt = tcnt, ot = osum;
    #pragma unroll
    for (int m = 1; m < 64; m <<= 1) {
        tt += __shfl_xor(tt, m, 64);
        ot += __shfl_xor(ot, m, 64);
    }
    if (lane < C_CLS) {
        out[(size_t)B_Q * C_CLS + q * C_CLS + lane]     = tcnt / (tt + EPSF);
        out[(size_t)2 * B_Q * C_CLS + q * C_CLS + lane] = osum / (ot + EPSF);
    }

    // logits = TAU * Xn_q . cn_c  (fp32 path)
    const float* zr = zn + (size_t)q * DIM;
    float zv[8];
    #pragma unroll
    for (int i = 0; i < 8; ++i) zv[i] = zr[lane + 64 * i];
    #pragma unroll
    for (int c = 0; c < C_CLS; ++c) {
        float d = 0.f;
        #pragma unroll
        for (int i = 0; i < 8; ++i) d += zv[i] * cn[c * DIM + lane + 64 * i];
        #pragma unroll
        for (int m = 1; m < 64; m <<= 1) d += __shfl_xor(d, m, 64);
        if (lane == 0) out[q * C_CLS + c] = TAU_F * d;
    }
}

// ======================= launcher =======================
extern "C" void kernel_launch(void* const* d_in, const int* in_sizes, int n_in,
                              void* d_out, int out_size, void* d_ws, size_t ws_size,
                              hipStream_t stream)
{
    const float* z        = (const float*)d_in[0];
    const float* supports = (const float*)d_in[1];
    const float* labels   = (const float*)d_in[2];
    float* ws  = (float*)d_ws;
    float* out = (float*)d_out;

    float*     part   = ws + WS_PART;
    float*     pcnt   = ws + WS_PCNT;
    float*     cn     = ws + WS_CN;
    float*     yyv    = ws + WS_YY;
    int*       cls    = (int*)(ws + WS_CLS);
    float*     p      = ws + WS_P;
    float*     zn     = ws + WS_ZN;
    float*     xx     = ws + WS_XX;
    float*     cand_s = ws + WS_CANDS;
    int*       cand_i = (int*)(ws + WS_CANDI);
    _Float16*  znh    = (_Float16*)(ws + WS_ZNH);
    _Float16*  znl    = (_Float16*)(ws + WS_ZNL);
    _Float16*  suph   = (_Float16*)(ws + WS_SUPH);
    _Float16*  supl   = (_Float16*)(ws + WS_SUPL);

    hipLaunchKernelGGL(k_centroid_accum, dim3(64), dim3(256), 0, stream,
                       supports, labels, part, pcnt);
    hipLaunchKernelGGL(k_centroid_fin, dim3(17), dim3(256), 0, stream,
                       part, pcnt, cn);
    hipLaunchKernelGGL(k_support_stats, dim3(N_S / 4), dim3(256), 0, stream,
                       supports, cn, yyv, cls, p, suph, supl);
    hipLaunchKernelGGL(k_query_norm, dim3(B_Q / 4), dim3(256), 0, stream,
                       z, zn, xx, znh, znl);
    hipLaunchKernelGGL(k_score_mfma, dim3(1024), dim3(256), 0, stream,
                       znh, znl, suph, supl, yyv, xx, cand_s, cand_i);
    hipLaunchKernelGGL(k_merge_out, dim3(B_Q / 4), dim3(256), 0, stream,
                       cand_s, cand_i, cls, p, zn, cn, out);
}

// Round 3
// 521.777 us; speedup vs baseline: 4.5808x; 1.1088x over previous
//
#include <hip/hip_runtime.h>
#include <float.h>
#include <math.h>

// Problem constants (fixed by setup_inputs)
#define B_Q   2048
#define N_S   16384
#define DIM   512
#define C_CLS 17
#define K_TOP 8
#define TAU_F 10.0f
#define EPSF  1e-12f

typedef _Float16 f16x8 __attribute__((ext_vector_type(8)));
typedef float    f32x16 __attribute__((ext_vector_type(16)));

#define GLDS(gp, lp) __builtin_amdgcn_global_load_lds( \
    (const __attribute__((address_space(1))) void*)(gp), \
    (__attribute__((address_space(3))) void*)(lp), 16, 0, 0)

// ---- workspace layout (in floats) ----
// Split-f16 arrays are TILED: element (row n, k) lives at
//   [(c*4+g)*NROWS + n]*8 + (k&7),  c = k>>5, g = (k>>3)&3
// i.e. the exact image of the GEMM's LDS staging layout -> 1KB contiguous
// per global_load_lds instruction (16 full lines, fully coalesced).
#define WS_CN     0            // 17*512
#define WS_YY     8704         // N
#define WS_CLS    25088        // N (int)
#define WS_P      41472        // N*17
#define WS_ZN     320000       // B*D fp32 (logits path)
#define WS_XX     1368576      // B
#define WS_CANDS  1370624      // B*1024
#define WS_CANDI  3467776      // B*1024 (int)
#define WS_ZNH    5564928      // B*D f16 tiled (524288 floats)
#define WS_ZNL    6089216      // B*D f16 tiled
#define WS_SUPH   6613504      // N*D f16 tiled (4194304 floats)
#define WS_SUPL   10807808     // N*D f16 tiled
// total 15,002,112 floats = 60.0 MB
// centroid partials alias into the cand region (consumed before cands exist):
#define WS_PARTA  WS_CANDS                 // 256 * 8704
#define WS_PCNTA  (WS_CANDS + 2228224)     // 256 * 32

// ======================= centroid partial accumulation =======================
__global__ __launch_bounds__(256) void k_centroid_accum(
    const float* __restrict__ supports, const float* __restrict__ labels,
    float* __restrict__ part, float* __restrict__ pcnt)
{
    __shared__ float acc[C_CLS * DIM];
    __shared__ float lcnt[C_CLS];
    __shared__ int   lcls[64];
    const int tid = threadIdx.x;
    for (int i = tid; i < C_CLS * DIM; i += 256) acc[i] = 0.f;
    if (tid < C_CLS) lcnt[tid] = 0.f;
    __syncthreads();
    if (tid < 64) {
        const int n = blockIdx.x * 64 + tid;
        float best = labels[n * C_CLS + 0];
        int bc = 0;
        #pragma unroll
        for (int c = 1; c < C_CLS; ++c) {
            float v = labels[n * C_CLS + c];
            if (v > best) { best = v; bc = c; }
        }
        lcls[tid] = bc;
        atomicAdd(&lcnt[bc], best);   // best == 1.0 (one-hot)
    }
    __syncthreads();
    const int d0 = tid, d1 = tid + 256;
    const int base = blockIdx.x * 64;
    for (int r = 0; r < 64; ++r) {
        const int c = lcls[r];
        const float* srow = supports + (size_t)(base + r) * DIM;
        acc[c * DIM + d0] += srow[d0];
        acc[c * DIM + d1] += srow[d1];
    }
    __syncthreads();
    float* pout = part + (size_t)blockIdx.x * (C_CLS * DIM);
    for (int i = tid; i < C_CLS * DIM; i += 256) pout[i] = acc[i];
    if (tid < C_CLS) pcnt[blockIdx.x * 32 + tid] = lcnt[tid];
}

// ======================= centroid finalize (normalize) =======================
__global__ __launch_bounds__(256) void k_centroid_fin(
    const float* __restrict__ part, const float* __restrict__ pcnt,
    float* __restrict__ cn)
{
    __shared__ float red[4];
    const int c = blockIdx.x, tid = threadIdx.x;
    float cntv = 0.f;
    for (int b = 0; b < 256; ++b) cntv += pcnt[b * 32 + c];
    const float denc = cntv + EPSF;
    float v0 = 0.f, v1 = 0.f;
    for (int b = 0; b < 256; ++b) {
        const float* pb = part + (size_t)b * (C_CLS * DIM) + c * DIM;
        v0 += pb[tid];
        v1 += pb[tid + 256];
    }
    v0 /= denc;
    v1 /= denc;
    float ss = v0 * v0 + v1 * v1;
    #pragma unroll
    for (int m = 1; m < 64; m <<= 1) ss += __shfl_xor(ss, m, 64);
    if ((tid & 63) == 0) red[tid >> 6] = ss;
    __syncthreads();
    const float tot = red[0] + red[1] + red[2] + red[3];
    const float den = fmaxf(sqrtf(tot), EPSF);
    cn[c * DIM + tid]       = v0 / den;
    cn[c * DIM + 256 + tid] = v1 / den;
}

// ==== per-support: norm -> tiled f16 hi/lo, yy, temp_labels -> argmax+softmax
__global__ __launch_bounds__(256) void k_support_stats(
    const float* __restrict__ supports, const float* __restrict__ cn,
    float* __restrict__ yy, int* __restrict__ cls, float* __restrict__ p,
    _Float16* __restrict__ suph, _Float16* __restrict__ supl)
{
    __shared__ float cnl[C_CLS * DIM];
    __shared__ float ynl[4 * DIM];
    const int tid = threadIdx.x;
    for (int i = tid; i < C_CLS * DIM; i += 256) cnl[i] = cn[i];

    const int w = tid >> 6, lane = tid & 63;
    const int n = blockIdx.x * 4 + w;
    const float* srow = supports + (size_t)n * DIM;

    float s[8];
    #pragma unroll
    for (int i = 0; i < 8; ++i) s[i] = srow[lane + 64 * i];
    float ss = 0.f;
    #pragma unroll
    for (int i = 0; i < 8; ++i) ss += s[i] * s[i];
    #pragma unroll
    for (int m = 1; m < 64; m <<= 1) ss += __shfl_xor(ss, m, 64);
    const float den = fmaxf(sqrtf(ss), EPSF);

    float yn[8];
    float y2 = 0.f;
    #pragma unroll
    for (int i = 0; i < 8; ++i) {
        yn[i] = s[i] / den;
        ynl[w * DIM + lane + 64 * i] = yn[i];
        y2 += yn[i] * yn[i];
    }
    #pragma unroll
    for (int m = 1; m < 64; m <<= 1) y2 += __shfl_xor(y2, m, 64);

    __syncthreads();   // cnl + ynl ready

    float tl[C_CLS];
    #pragma unroll
    for (int c = 0; c < C_CLS; ++c) {
        float d = 0.f;
        #pragma unroll
        for (int i = 0; i < 8; ++i) d += yn[i] * cnl[c * DIM + lane + 64 * i];
        #pragma unroll
        for (int m = 1; m < 64; m <<= 1) d += __shfl_xor(d, m, 64);
        tl[c] = TAU_F * d;
    }
    float mx = tl[0];
    int am = 0;
    #pragma unroll
    for (int c = 1; c < C_CLS; ++c)
        if (tl[c] > mx) { mx = tl[c]; am = c; }
    float e[C_CLS];
    float sum = 0.f;
    #pragma unroll
    for (int c = 0; c < C_CLS; ++c) { e[c] = expf(tl[c] - mx); sum += e[c]; }

    if (lane == 0) {
        yy[n]  = y2;
        cls[n] = am;
        #pragma unroll
        for (int c = 0; c < C_CLS; ++c) p[n * C_CLS + c] = e[c] / sum;
    }

    // tiled hi/lo writes: thread t -> chunk cg = t>>2, row = t&3.
    // Per wave: 16 cgs x 4 rows x 16B = 16 full 64B lines (optimal).
    {
        const int row = tid & 3, cg = tid >> 2;
        const float* yrow = ynl + row * DIM + cg * 8;
        f16x8 hi, lo;
        #pragma unroll
        for (int j = 0; j < 8; ++j) {
            const float v = yrow[j];
            const _Float16 hh = (_Float16)v;
            hi[j] = hh;
            lo[j] = (_Float16)(v - (float)hh);
        }
        const size_t off = ((size_t)cg * N_S + blockIdx.x * 4 + row) * 8;
        *(f16x8*)(suph + off) = hi;
        *(f16x8*)(supl + off) = lo;
    }
}

// ======================= query normalize + tiled f16 split ===================
__global__ __launch_bounds__(256) void k_query_norm(
    const float* __restrict__ z, float* __restrict__ zn, float* __restrict__ xx,
    _Float16* __restrict__ znh, _Float16* __restrict__ znl)
{
    __shared__ float ynl[4 * DIM];
    const int tid = threadIdx.x, w = tid >> 6, lane = tid & 63;
    const int q = blockIdx.x * 4 + w;
    const float* zr = z + (size_t)q * DIM;
    float s[8];
    float ss = 0.f;
    #pragma unroll
    for (int i = 0; i < 8; ++i) { s[i] = zr[lane + 64 * i]; ss += s[i] * s[i]; }
    #pragma unroll
    for (int m = 1; m < 64; m <<= 1) ss += __shfl_xor(ss, m, 64);
    const float den = fmaxf(sqrtf(ss), EPSF);
    float x2 = 0.f;
    #pragma unroll
    for (int i = 0; i < 8; ++i) {
        const float v = s[i] / den;
        zn[(size_t)q * DIM + lane + 64 * i] = v;
        ynl[w * DIM + lane + 64 * i] = v;
        x2 += v * v;
    }
    #pragma unroll
    for (int m = 1; m < 64; m <<= 1) x2 += __shfl_xor(x2, m, 64);
    if (lane == 0) xx[q] = x2;
    __syncthreads();
    {
        const int row = tid & 3, cg = tid >> 2;
        const float* yrow = ynl + row * DIM + cg * 8;
        f16x8 hi, lo;
        #pragma unroll
        for (int j = 0; j < 8; ++j) {
            const float v = yrow[j];
            const _Float16 hh = (_Float16)v;
            hi[j] = hh;
            lo[j] = (_Float16)(v - (float)hh);
        }
        const size_t off = ((size_t)cg * B_Q + blockIdx.x * 4 + row) * 8;
        *(f16x8*)(znh + off) = hi;
        *(f16x8*)(znl + off) = lo;
    }
}

// ============ MFMA split-f16 score GEMM + fused per-range top-8 ============
// Block tile 128(q) x 256(s), BK=32. 4 waves, each 64x128 (2x4 of 32x32).
// Staging: tiled-global -> 1KB contiguous per global_load_lds (coalesced).
__global__ __launch_bounds__(256, 2) void k_score_mfma(
    const _Float16* __restrict__ znh, const _Float16* __restrict__ znl,
    const _Float16* __restrict__ suph, const _Float16* __restrict__ supl,
    const float* __restrict__ yy, const float* __restrict__ xx,
    float* __restrict__ cand_s, int* __restrict__ cand_i)
{
    __shared__ __align__(16) _Float16 lds[24576];   // 48 KB
    _Float16* Ah = lds;
    _Float16* Al = lds + 4096;
    _Float16* Bh = lds + 8192;
    _Float16* Bl = lds + 16384;

    const int tid = threadIdx.x;
    const int w = tid >> 6, l = tid & 63;
    const int h = l >> 5, ln = l & 31;
    const int bm = blockIdx.x & 15;
    const int bn = blockIdx.x >> 4;
    const int q0 = bm * 128, s0 = bn * 256;
    const int wm = w & 1, wn = w >> 1;

    // 12 staging streams per wave; per-chunk advance is a constant stride.
    const _Float16* src[12];
    _Float16*       dst[12];
    int             strd[12];
    #pragma unroll
    for (int i = 0; i < 12; ++i) {
        const int t = w + 4 * i;   // wave-uniform 0..47
        if (t < 16) {
            const int half = t >> 3, a = t & 7, g = a >> 1, r0 = (a & 1) << 6;
            src[i]  = (half ? znl : znh) + ((size_t)g * B_Q + q0 + r0 + l) * 8;
            dst[i]  = (half ? Al : Ah) + (g * 128 + r0) * 8;
            strd[i] = 4 * B_Q * 8;
        } else {
            const int tb = t - 16, half = tb >> 4, b = tb & 15, g = b >> 2, r0 = (b & 3) << 6;
            src[i]  = (half ? supl : suph) + ((size_t)g * N_S + s0 + r0 + l) * 8;
            dst[i]  = (half ? Bl : Bh) + (g * 256 + r0) * 8;
            strd[i] = 4 * N_S * 8;
        }
    }

    f32x16 acc[2][4];
    #pragma unroll
    for (int t = 0; t < 2; ++t)
        #pragma unroll
        for (int u = 0; u < 4; ++u)
            #pragma unroll
            for (int e = 0; e < 16; ++e) acc[t][u][e] = 0.f;

    for (int chunk = 0; chunk < 16; ++chunk) {
        __syncthreads();   // previous chunk's frag reads complete
        #pragma unroll
        for (int i = 0; i < 12; ++i) {
            GLDS(src[i], dst[i]);
            src[i] += strd[i];
        }
        __syncthreads();   // staging visible (barrier drains vmcnt)

        #pragma unroll
        for (int kk = 0; kk < 2; ++kk) {
            const int g8 = kk * 2 + h;
            f16x8 ah[2], al[2], bh[4], bl[4];
            #pragma unroll
            for (int t = 0; t < 2; ++t) {
                ah[t] = *(const f16x8*)(Ah + (size_t)(g8 * 128 + wm * 64 + t * 32 + ln) * 8);
                al[t] = *(const f16x8*)(Al + (size_t)(g8 * 128 + wm * 64 + t * 32 + ln) * 8);
            }
            #pragma unroll
            for (int u = 0; u < 4; ++u) {
                bh[u] = *(const f16x8*)(Bh + (size_t)(g8 * 256 + wn * 128 + u * 32 + ln) * 8);
                bl[u] = *(const f16x8*)(Bl + (size_t)(g8 * 256 + wn * 128 + u * 32 + ln) * 8);
            }
            #pragma unroll
            for (int t = 0; t < 2; ++t)
                #pragma unroll
                for (int u = 0; u < 4; ++u) {
                    acc[t][u] = __builtin_amdgcn_mfma_f32_32x32x16_f16(ah[t], bh[u], acc[t][u], 0, 0, 0);
                    acc[t][u] = __builtin_amdgcn_mfma_f32_32x32x16_f16(ah[t], bl[u], acc[t][u], 0, 0, 0);
                    acc[t][u] = __builtin_amdgcn_mfma_f32_32x32x16_f16(al[t], bh[u], acc[t][u], 0, 0, 0);
                }
        }
    }

    // ---------------- epilogue: dist -> exp -> top-8 per (q, 128-col range) ----
    float* sw = ((float*)lds) + w * 3072;   // 12 KB per-wave scratch
    const int row16 = l & 15, seg = l >> 4;
    const int range = bn * 2 + wn;

    float yv[32];
    #pragma unroll
    for (int j = 0; j < 32; ++j) {
        const int cc = seg * 32 + ((j + seg * 8) & 31);
        yv[j] = yy[s0 + wn * 128 + cc];
    }

    #pragma unroll
    for (int p = 0; p < 4; ++p) {
        const int t = p >> 1, rb = (p & 1) * 8;
        __syncthreads();   // prior pass merge reads done / K-loop reads done
        #pragma unroll
        for (int q = 0; q < 8; ++q) {
            const int lr = (q & 3) + 8 * (q >> 2) + 4 * h;
            #pragma unroll
            for (int u = 0; u < 4; ++u)
                sw[lr * 129 + u * 32 + ln] = acc[t][u][rb + q];
        }
        __syncthreads();

        float ts[8]; int ti[8];
        float tmn = -FLT_MAX; int tmni = 0x7fffffff; int tmns = 0;
        #pragma unroll
        for (int r = 0; r < 8; ++r) { ts[r] = -FLT_MAX; ti[r] = 0x7fffffff; }
        const int qg = q0 + wm * 64 + p * 16 + row16;
        const float xq = xx[qg];
        for (int j = 0; j < 32; ++j) {
            const int cc = seg * 32 + ((j + seg * 8) & 31);
            const float cv = sw[row16 * 129 + cc];
            const int sg = s0 + wn * 128 + cc;
            const float dist = xq + yv[j] - 2.0f * cv;
            const float sc = expf(-dist);
            const bool better = (sc > tmn) || ((sc == tmn) && (sg < tmni));
            if (better) {
                #pragma unroll
                for (int r = 0; r < 8; ++r)
                    if (r == tmns) { ts[r] = sc; ti[r] = sg; }
                float ms = ts[0]; int mi = ti[0]; int msl = 0;
                #pragma unroll
                for (int r = 1; r < 8; ++r) {
                    const bool wrs = (ts[r] < ms) || ((ts[r] == ms) && (ti[r] > mi));
                    if (wrs) { ms = ts[r]; mi = ti[r]; msl = r; }
                }
                tmn = ms; tmni = mi; tmns = msl;
            }
        }
        __syncthreads();
        #pragma unroll
        for (int r = 0; r < 8; ++r) {
            sw[l * 17 + r] = ts[r];
            ((int*)sw)[l * 17 + 8 + r] = ti[r];
        }
        __syncthreads();
        if (l < 16) {
            float bs[8]; int bi[8];
            float mn = -FLT_MAX; int mni = 0x7fffffff; int mns = 0;
            #pragma unroll
            for (int r = 0; r < 8; ++r) { bs[r] = -FLT_MAX; bi[r] = 0x7fffffff; }
            for (int k = 0; k < 4; ++k) {
                const int off = (l + 16 * k) * 17;
                #pragma unroll
                for (int r = 0; r < 8; ++r) {
                    const float sc = sw[off + r];
                    const int   sj = ((int*)sw)[off + 8 + r];
                    const bool better = (sc > mn) || ((sc == mn) && (sj < mni));
                    if (better) {
                        #pragma unroll
                        for (int u = 0; u < 8; ++u)
                            if (u == mns) { bs[u] = sc; bi[u] = sj; }
                        float ms = bs[0]; int mi = bi[0]; int msl = 0;
                        #pragma unroll
                        for (int u = 1; u < 8; ++u) {
                            const bool wrs = (bs[u] < ms) || ((bs[u] == ms) && (bi[u] > mi));
                            if (wrs) { ms = bs[u]; mi = bi[u]; msl = u; }
                        }
                        mn = ms; mni = mi; mns = msl;
                    }
                }
            }
            #pragma unroll
            for (int r = 0; r < 8; ++r) {
                cand_s[(size_t)qg * 1024 + range * 8 + r] = bs[r];
                cand_i[(size_t)qg * 1024 + range * 8 + r] = bi[r];
            }
        }
    }
}

// ======================= final merge + outputs + logits =======================
__global__ __launch_bounds__(256) void k_merge_out(
    const float* __restrict__ cand_s, const int* __restrict__ cand_i,
    const int* __restrict__ cls, const float* __restrict__ p,
    const float* __restrict__ zn, const float* __restrict__ cn,
    float* __restrict__ out)
{
    const int tid = threadIdx.x, w = tid >> 6, lane = tid & 63;
    const int q = blockIdx.x * 4 + w;

    float ts[8]; int ti[8];
    #pragma unroll
    for (int r = 0; r < 8; ++r) { ts[r] = -FLT_MAX; ti[r] = 0x7fffffff; }
    for (int j = 0; j < 16; ++j) {
        const float sc = cand_s[(size_t)q * 1024 + j * 64 + lane];
        const int   si = cand_i[(size_t)q * 1024 + j * 64 + lane];
        float mn = ts[0]; int mni = ti[0]; int slot = 0;
        #pragma unroll
        for (int r = 1; r < 8; ++r) {
            const bool wrs = (ts[r] < mn) || ((ts[r] == mn) && (ti[r] > mni));
            if (wrs) { mn = ts[r]; mni = ti[r]; slot = r; }
        }
        const bool better = (sc > mn) || ((sc == mn) && (si < mni));
        if (better) {
            #pragma unroll
            for (int r = 0; r < 8; ++r)
                if (r == slot) { ts[r] = sc; ti[r] = si; }
        }
    }

    float tcnt = 0.f, osum = 0.f;
    #pragma unroll
    for (int r = 0; r < K_TOP; ++r) {
        float mv = ts[0]; int mi = ti[0]; int ms = 0;
        #pragma unroll
        for (int u = 1; u < 8; ++u) {
            const bool b = (ts[u] > mv) || ((ts[u] == mv) && (ti[u] < mi));
            if (b) { mv = ts[u]; mi = ti[u]; ms = u; }
        }
        float bv = mv; int bi = mi;
        #pragma unroll
        for (int m = 1; m < 64; m <<= 1) {
            const float ov = __shfl_xor(bv, m, 64);
            const int   oi = __shfl_xor(bi, m, 64);
            const bool take = (ov > bv) || ((ov == bv) && (oi < bi));
            if (take) { bv = ov; bi = oi; }
        }
        if (mv == bv && mi == bi) {
            #pragma unroll
            for (int u = 0; u < 8; ++u)
                if (u == ms) { ts[u] = -FLT_MAX; ti[u] = 0x7fffffff; }
        }
        const int cw = cls[bi];
        if (lane < C_CLS) {
            osum += p[bi * C_CLS + lane];
            tcnt += (cw == lane) ? 1.0f : 0.f;
        }
    }
    float tt = tcnt, ot = osum;
    #pragma unroll
    for (int m = 1; m < 64; m <<= 1) {
        tt += __shfl_xor(tt, m, 64);
        ot += __shfl_xor(ot, m, 64);
    }
    if (lane < C_CLS) {
        out[(size_t)B_Q * C_CLS + q * C_CLS + lane]     = tcnt / (tt + EPSF);
        out[(size_t)2 * B_Q * C_CLS + q * C_CLS + lane] = osum / (ot + EPSF);
    }

    // logits = TAU * Xn_q . cn_c  (fp32 path)
    const float* zr = zn + (size_t)q * DIM;
    float zv[8];
    #pragma unroll
    for (int i = 0; i < 8; ++i) zv[i] = zr[lane + 64 * i];
    #pragma unroll
    for (int c = 0; c < C_CLS; ++c) {
        float d = 0.f;
        #pragma unroll
        for (int i = 0; i < 8; ++i) d += zv[i] * cn[c * DIM + lane + 64 * i];
        #pragma unroll
        for (int m = 1; m < 64; m <<= 1) d += __shfl_xor(d, m, 64);
        if (lane == 0) out[q * C_CLS + c] = TAU_F * d;
    }
}

// ======================= launcher =======================
extern "C" void kernel_launch(void* const* d_in, const int* in_sizes, int n_in,
                              void* d_out, int out_size, void* d_ws, size_t ws_size,
                              hipStream_t stream)
{
    const float* z        = (const float*)d_in[0];
    const float* supports = (const float*)d_in[1];
    const float* labels   = (const float*)d_in[2];
    float* ws  = (float*)d_ws;
    float* out = (float*)d_out;

    float*     part   = ws + WS_PARTA;
    float*     pcnt   = ws + WS_PCNTA;
    float*     cn     = ws + WS_CN;
    float*     yyv    = ws + WS_YY;
    int*       cls    = (int*)(ws + WS_CLS);
    float*     p      = ws + WS_P;
    float*     zn     = ws + WS_ZN;
    float*     xx     = ws + WS_XX;
    float*     cand_s = ws + WS_CANDS;
    int*       cand_i = (int*)(ws + WS_CANDI);
    _Float16*  znh    = (_Float16*)(ws + WS_ZNH);
    _Float16*  znl    = (_Float16*)(ws + WS_ZNL);
    _Float16*  suph   = (_Float16*)(ws + WS_SUPH);
    _Float16*  supl   = (_Float16*)(ws + WS_SUPL);

    hipLaunchKernelGGL(k_centroid_accum, dim3(256), dim3(256), 0, stream,
                       supports, labels, part, pcnt);
    hipLaunchKernelGGL(k_centroid_fin, dim3(17), dim3(256), 0, stream,
                       part, pcnt, cn);
    hipLaunchKernelGGL(k_support_stats, dim3(N_S / 4), dim3(256), 0, stream,
                       supports, cn, yyv, cls, p, suph, supl);
    hipLaunchKernelGGL(k_query_norm, dim3(B_Q / 4), dim3(256), 0, stream,
                       z, zn, xx, znh, znl);
    hipLaunchKernelGGL(k_score_mfma, dim3(1024), dim3(256), 0, stream,
                       znh, znl, suph, supl, yyv, xx, cand_s, cand_i);
    hipLaunchKernelGGL(k_merge_out, dim3(B_Q / 4), dim3(256), 0, stream,
                       cand_s, cand_i, cls, p, zn, cn, out);
}

// Round 4
// 502.558 us; speedup vs baseline: 4.7559x; 1.0382x over previous
//
#include <hip/hip_runtime.h>
#include <float.h>
#include <math.h>

// Problem constants (fixed by setup_inputs)
#define B_Q   2048
#define N_S   16384
#define DIM   512
#define C_CLS 17
#define K_TOP 8
#define TAU_F 10.0f
#define EPSF  1e-12f

typedef _Float16 f16x8 __attribute__((ext_vector_type(8)));
typedef float    f32x16 __attribute__((ext_vector_type(16)));

#define GLDS(gp, lp) __builtin_amdgcn_global_load_lds( \
    (const __attribute__((address_space(1))) void*)(gp), \
    (__attribute__((address_space(3))) void*)(lp), 16, 0, 0)

// ---- workspace layout (in floats) ----
// Split-f16 arrays are TILED: element (row n, k) lives at
//   [g*NROWS + n]*8 + (k&7),  g = k>>3  (8-wide k-groups)
// i.e. the exact image of the GEMM's LDS staging layout -> 1KB contiguous
// per global_load_lds instruction (16 full lines, fully coalesced).
#define WS_CN     0            // 17*512
#define WS_YY     8704         // N
#define WS_CLS    25088        // N (int)
#define WS_P      41472        // N*17
#define WS_ZN     320000       // B*D fp32 (logits path)
#define WS_XX     1368576      // B
#define WS_CANDS  1370624      // B*1024
#define WS_CANDI  3467776      // B*1024 (int)
#define WS_ZNH    5564928      // B*D f16 tiled (524288 floats)
#define WS_ZNL    6089216      // B*D f16 tiled
#define WS_SUPH   6613504      // N*D f16 tiled (4194304 floats)
#define WS_SUPL   10807808     // N*D f16 tiled
// total 15,002,112 floats = 60.0 MB
// centroid partials alias into the cand region (consumed before cands exist):
#define WS_PARTA  WS_CANDS                 // 256 * 8704
#define WS_PCNTA  (WS_CANDS + 2228224)     // 256 * 32

// ======================= centroid partial accumulation =======================
__global__ __launch_bounds__(256) void k_centroid_accum(
    const float* __restrict__ supports, const float* __restrict__ labels,
    float* __restrict__ part, float* __restrict__ pcnt)
{
    __shared__ float acc[C_CLS * DIM];
    __shared__ float lcnt[C_CLS];
    __shared__ int   lcls[64];
    const int tid = threadIdx.x;
    for (int i = tid; i < C_CLS * DIM; i += 256) acc[i] = 0.f;
    if (tid < C_CLS) lcnt[tid] = 0.f;
    __syncthreads();
    if (tid < 64) {
        const int n = blockIdx.x * 64 + tid;
        float best = labels[n * C_CLS + 0];
        int bc = 0;
        #pragma unroll
        for (int c = 1; c < C_CLS; ++c) {
            float v = labels[n * C_CLS + c];
            if (v > best) { best = v; bc = c; }
        }
        lcls[tid] = bc;
        atomicAdd(&lcnt[bc], best);   // best == 1.0 (one-hot)
    }
    __syncthreads();
    const int d0 = tid, d1 = tid + 256;
    const int base = blockIdx.x * 64;
    for (int r = 0; r < 64; ++r) {
        const int c = lcls[r];
        const float* srow = supports + (size_t)(base + r) * DIM;
        acc[c * DIM + d0] += srow[d0];
        acc[c * DIM + d1] += srow[d1];
    }
    __syncthreads();
    float* pout = part + (size_t)blockIdx.x * (C_CLS * DIM);
    for (int i = tid; i < C_CLS * DIM; i += 256) pout[i] = acc[i];
    if (tid < C_CLS) pcnt[blockIdx.x * 32 + tid] = lcnt[tid];
}

// ======================= centroid finalize (normalize) =======================
__global__ __launch_bounds__(256) void k_centroid_fin(
    const float* __restrict__ part, const float* __restrict__ pcnt,
    float* __restrict__ cn)
{
    __shared__ float red[4];
    const int c = blockIdx.x, tid = threadIdx.x;
    float cntv = 0.f;
    for (int b = 0; b < 256; ++b) cntv += pcnt[b * 32 + c];
    const float denc = cntv + EPSF;
    float v0 = 0.f, v1 = 0.f;
    for (int b = 0; b < 256; ++b) {
        const float* pb = part + (size_t)b * (C_CLS * DIM) + c * DIM;
        v0 += pb[tid];
        v1 += pb[tid + 256];
    }
    v0 /= denc;
    v1 /= denc;
    float ss = v0 * v0 + v1 * v1;
    #pragma unroll
    for (int m = 1; m < 64; m <<= 1) ss += __shfl_xor(ss, m, 64);
    if ((tid & 63) == 0) red[tid >> 6] = ss;
    __syncthreads();
    const float tot = red[0] + red[1] + red[2] + red[3];
    const float den = fmaxf(sqrtf(tot), EPSF);
    cn[c * DIM + tid]       = v0 / den;
    cn[c * DIM + 256 + tid] = v1 / den;
}

// ==== per-support: norm -> tiled f16 hi/lo, yy, temp_labels -> argmax+softmax
__global__ __launch_bounds__(256) void k_support_stats(
    const float* __restrict__ supports, const float* __restrict__ cn,
    float* __restrict__ yy, int* __restrict__ cls, float* __restrict__ p,
    _Float16* __restrict__ suph, _Float16* __restrict__ supl)
{
    __shared__ float cnl[C_CLS * DIM];
    __shared__ float ynl[4 * DIM];
    const int tid = threadIdx.x;
    for (int i = tid; i < C_CLS * DIM; i += 256) cnl[i] = cn[i];

    const int w = tid >> 6, lane = tid & 63;
    const int n = blockIdx.x * 4 + w;
    const float* srow = supports + (size_t)n * DIM;

    float s[8];
    #pragma unroll
    for (int i = 0; i < 8; ++i) s[i] = srow[lane + 64 * i];
    float ss = 0.f;
    #pragma unroll
    for (int i = 0; i < 8; ++i) ss += s[i] * s[i];
    #pragma unroll
    for (int m = 1; m < 64; m <<= 1) ss += __shfl_xor(ss, m, 64);
    const float den = fmaxf(sqrtf(ss), EPSF);

    float yn[8];
    float y2 = 0.f;
    #pragma unroll
    for (int i = 0; i < 8; ++i) {
        yn[i] = s[i] / den;
        ynl[w * DIM + lane + 64 * i] = yn[i];
        y2 += yn[i] * yn[i];
    }
    #pragma unroll
    for (int m = 1; m < 64; m <<= 1) y2 += __shfl_xor(y2, m, 64);

    __syncthreads();   // cnl + ynl ready

    float tl[C_CLS];
    #pragma unroll
    for (int c = 0; c < C_CLS; ++c) {
        float d = 0.f;
        #pragma unroll
        for (int i = 0; i < 8; ++i) d += yn[i] * cnl[c * DIM + lane + 64 * i];
        #pragma unroll
        for (int m = 1; m < 64; m <<= 1) d += __shfl_xor(d, m, 64);
        tl[c] = TAU_F * d;
    }
    float mx = tl[0];
    int am = 0;
    #pragma unroll
    for (int c = 1; c < C_CLS; ++c)
        if (tl[c] > mx) { mx = tl[c]; am = c; }
    float e[C_CLS];
    float sum = 0.f;
    #pragma unroll
    for (int c = 0; c < C_CLS; ++c) { e[c] = expf(tl[c] - mx); sum += e[c]; }

    if (lane == 0) {
        yy[n]  = y2;
        cls[n] = am;
        #pragma unroll
        for (int c = 0; c < C_CLS; ++c) p[n * C_CLS + c] = e[c] / sum;
    }

    // tiled hi/lo writes: thread t -> k-group cg = t>>2, row = t&3.
    {
        const int row = tid & 3, cg = tid >> 2;
        const float* yrow = ynl + row * DIM + cg * 8;
        f16x8 hi, lo;
        #pragma unroll
        for (int j = 0; j < 8; ++j) {
            const float v = yrow[j];
            const _Float16 hh = (_Float16)v;
            hi[j] = hh;
            lo[j] = (_Float16)(v - (float)hh);
        }
        const size_t off = ((size_t)cg * N_S + blockIdx.x * 4 + row) * 8;
        *(f16x8*)(suph + off) = hi;
        *(f16x8*)(supl + off) = lo;
    }
}

// ======================= query normalize + tiled f16 split ===================
__global__ __launch_bounds__(256) void k_query_norm(
    const float* __restrict__ z, float* __restrict__ zn, float* __restrict__ xx,
    _Float16* __restrict__ znh, _Float16* __restrict__ znl)
{
    __shared__ float ynl[4 * DIM];
    const int tid = threadIdx.x, w = tid >> 6, lane = tid & 63;
    const int q = blockIdx.x * 4 + w;
    const float* zr = z + (size_t)q * DIM;
    float s[8];
    float ss = 0.f;
    #pragma unroll
    for (int i = 0; i < 8; ++i) { s[i] = zr[lane + 64 * i]; ss += s[i] * s[i]; }
    #pragma unroll
    for (int m = 1; m < 64; m <<= 1) ss += __shfl_xor(ss, m, 64);
    const float den = fmaxf(sqrtf(ss), EPSF);
    float x2 = 0.f;
    #pragma unroll
    for (int i = 0; i < 8; ++i) {
        const float v = s[i] / den;
        zn[(size_t)q * DIM + lane + 64 * i] = v;
        ynl[w * DIM + lane + 64 * i] = v;
        x2 += v * v;
    }
    #pragma unroll
    for (int m = 1; m < 64; m <<= 1) x2 += __shfl_xor(x2, m, 64);
    if (lane == 0) xx[q] = x2;
    __syncthreads();
    {
        const int row = tid & 3, cg = tid >> 2;
        const float* yrow = ynl + row * DIM + cg * 8;
        f16x8 hi, lo;
        #pragma unroll
        for (int j = 0; j < 8; ++j) {
            const float v = yrow[j];
            const _Float16 hh = (_Float16)v;
            hi[j] = hh;
            lo[j] = (_Float16)(v - (float)hh);
        }
        const size_t off = ((size_t)cg * B_Q + blockIdx.x * 4 + row) * 8;
        *(f16x8*)(znh + off) = hi;
        *(f16x8*)(znl + off) = lo;
    }
}

// ============ MFMA split-f16 score GEMM + fused per-range top-8 ============
// Block tile 128(q) x 256(s), BK=16, DOUBLE-BUFFERED staging (24 KB x 2).
// 4 waves, each 64x128 (2x4 of 32x32). Stage(c+1) issued after the barrier,
// before compute(c): the barrier at iter c+1 drains a load that had a full
// compute-chunk to land -> staging latency overlapped.
// Ranking key = acc - 0.5*yy (monotone-equivalent to exp(-dist); exp dropped).
#define BUFH 12288   // f16 elements per buffer (24 KB)

__global__ __launch_bounds__(256, 2) void k_score_mfma(
    const _Float16* __restrict__ znh, const _Float16* __restrict__ znl,
    const _Float16* __restrict__ suph, const _Float16* __restrict__ supl,
    const float* __restrict__ yy,
    float* __restrict__ cand_s, int* __restrict__ cand_i)
{
    __shared__ __align__(16) _Float16 lds[2 * BUFH];   // 48 KB

    const int tid = threadIdx.x;
    const int w = tid >> 6, l = tid & 63;
    const int h = l >> 5, ln = l & 31;
    const int bm = blockIdx.x & 15;
    const int bn = blockIdx.x >> 4;
    const int q0 = bm * 128, s0 = bn * 256;
    const int wm = w & 1, wn = w >> 1;

    // 6 staging streams per wave (24 per block per chunk).
    // Per-buffer layout (f16 idx): Ah@0 (2g x 128r x 8), Al@2048,
    //                              Bh@4096 (2g x 256r x 8), Bl@8192.
    const _Float16* src[6];
    int             dof[6];
    int             adv[6];
    #pragma unroll
    for (int i = 0; i < 6; ++i) {
        const int t = w + 4 * i;   // wave-uniform 0..23
        if (t < 8) {
            const int h2 = t >> 2, sub = t & 3, g = sub >> 1, rb = (sub & 1) << 6;
            src[i] = (h2 ? znl : znh) + ((size_t)g * B_Q + q0 + rb + l) * 8;
            dof[i] = h2 * 2048 + (g * 128 + rb + l) * 8;
            adv[i] = 2 * B_Q * 8;
        } else {
            const int u = t - 8, h2 = u >> 3, sub = u & 7, g = sub >> 2, rb = (sub & 3) << 6;
            src[i] = (h2 ? supl : suph) + ((size_t)g * N_S + s0 + rb + l) * 8;
            dof[i] = 4096 + h2 * 4096 + (g * 256 + rb + l) * 8;
            adv[i] = 2 * N_S * 8;
        }
    }

    f32x16 acc[2][4];
    #pragma unroll
    for (int t = 0; t < 2; ++t)
        #pragma unroll
        for (int u = 0; u < 4; ++u)
            #pragma unroll
            for (int e = 0; e < 16; ++e) acc[t][u][e] = 0.f;

    // prologue: stage chunk 0 into buffer 0
    #pragma unroll
    for (int i = 0; i < 6; ++i) { GLDS(src[i], lds + dof[i]); src[i] += adv[i]; }

    for (int c = 0; c < 32; ++c) {
        __syncthreads();   // drains stage(c) vmcnt + prior compute's lgkm
        if (c + 1 < 32) {
            _Float16* nb = lds + ((c + 1) & 1) * BUFH;
            #pragma unroll
            for (int i = 0; i < 6; ++i) { GLDS(src[i], nb + dof[i]); src[i] += adv[i]; }
        }
        const _Float16* base = lds + (c & 1) * BUFH;
        const _Float16* Ah = base;
        const _Float16* Al = base + 2048;
        const _Float16* Bh = base + 4096;
        const _Float16* Bl = base + 8192;

        f16x8 ah[2], al[2], bh[4], bl[4];
        #pragma unroll
        for (int t = 0; t < 2; ++t) {
            ah[t] = *(const f16x8*)(Ah + (size_t)(h * 128 + wm * 64 + t * 32 + ln) * 8);
            al[t] = *(const f16x8*)(Al + (size_t)(h * 128 + wm * 64 + t * 32 + ln) * 8);
        }
        #pragma unroll
        for (int u = 0; u < 4; ++u) {
            bh[u] = *(const f16x8*)(Bh + (size_t)(h * 256 + wn * 128 + u * 32 + ln) * 8);
            bl[u] = *(const f16x8*)(Bl + (size_t)(h * 256 + wn * 128 + u * 32 + ln) * 8);
        }
        #pragma unroll
        for (int t = 0; t < 2; ++t)
            #pragma unroll
            for (int u = 0; u < 4; ++u) {
                acc[t][u] = __builtin_amdgcn_mfma_f32_32x32x16_f16(ah[t], bh[u], acc[t][u], 0, 0, 0);
                acc[t][u] = __builtin_amdgcn_mfma_f32_32x32x16_f16(ah[t], bl[u], acc[t][u], 0, 0, 0);
                acc[t][u] = __builtin_amdgcn_mfma_f32_32x32x16_f16(al[t], bh[u], acc[t][u], 0, 0, 0);
            }
    }

    // ---------------- epilogue: key = acc - 0.5*yy -> top-8 per (q,128-col) ---
    float* sw = ((float*)lds) + w * 3072;   // 12 KB per-wave scratch
    const int row16 = l & 15, seg = l >> 4;
    const int range = bn * 2 + wn;

    float yv[32];
    #pragma unroll
    for (int j = 0; j < 32; ++j) {
        const int cc = seg * 32 + ((j + seg * 8) & 31);
        yv[j] = 0.5f * yy[s0 + wn * 128 + cc];
    }

    #pragma unroll
    for (int p = 0; p < 4; ++p) {
        const int t = p >> 1, rb = (p & 1) * 8;
        __syncthreads();   // prior pass merge reads done / K-loop reads done
        #pragma unroll
        for (int q = 0; q < 8; ++q) {
            const int lr = (q & 3) + 8 * (q >> 2) + 4 * h;
            #pragma unroll
            for (int u = 0; u < 4; ++u)
                sw[lr * 129 + u * 32 + ln] = acc[t][u][rb + q];
        }
        __syncthreads();

        float ts[8]; int ti[8];
        float tmn = -FLT_MAX; int tmni = 0x7fffffff; int tmns = 0;
        #pragma unroll
        for (int r = 0; r < 8; ++r) { ts[r] = -FLT_MAX; ti[r] = 0x7fffffff; }
        const int qg = q0 + wm * 64 + p * 16 + row16;
        for (int j = 0; j < 32; ++j) {
            const int cc = seg * 32 + ((j + seg * 8) & 31);
            const float cv = sw[row16 * 129 + cc];
            const int sg = s0 + wn * 128 + cc;
            const float sc = cv - yv[j];   // rank key (descending)
            const bool better = (sc > tmn) || ((sc == tmn) && (sg < tmni));
            if (better) {
                #pragma unroll
                for (int r = 0; r < 8; ++r)
                    if (r == tmns) { ts[r] = sc; ti[r] = sg; }
                float ms = ts[0]; int mi = ti[0]; int msl = 0;
                #pragma unroll
                for (int r = 1; r < 8; ++r) {
                    const bool wrs = (ts[r] < ms) || ((ts[r] == ms) && (ti[r] > mi));
                    if (wrs) { ms = ts[r]; mi = ti[r]; msl = r; }
                }
                tmn = ms; tmni = mi; tmns = msl;
            }
        }
        __syncthreads();
        #pragma unroll
        for (int r = 0; r < 8; ++r) {
            sw[l * 17 + r] = ts[r];
            ((int*)sw)[l * 17 + 8 + r] = ti[r];
        }
        __syncthreads();
        if (l < 16) {
            float bs[8]; int bi[8];
            float mn = -FLT_MAX; int mni = 0x7fffffff; int mns = 0;
            #pragma unroll
            for (int r = 0; r < 8; ++r) { bs[r] = -FLT_MAX; bi[r] = 0x7fffffff; }
            for (int k = 0; k < 4; ++k) {
                const int off = (l + 16 * k) * 17;
                #pragma unroll
                for (int r = 0; r < 8; ++r) {
                    const float sc = sw[off + r];
                    const int   sj = ((int*)sw)[off + 8 + r];
                    const bool better = (sc > mn) || ((sc == mn) && (sj < mni));
                    if (better) {
                        #pragma unroll
                        for (int u = 0; u < 8; ++u)
                            if (u == mns) { bs[u] = sc; bi[u] = sj; }
                        float ms = bs[0]; int mi = bi[0]; int msl = 0;
                        #pragma unroll
                        for (int u = 1; u < 8; ++u) {
                            const bool wrs = (bs[u] < ms) || ((bs[u] == ms) && (bi[u] > mi));
                            if (wrs) { ms = bs[u]; mi = bi[u]; msl = u; }
                        }
                        mn = ms; mni = mi; mns = msl;
                    }
                }
            }
            #pragma unroll
            for (int r = 0; r < 8; ++r) {
                cand_s[(size_t)qg * 1024 + range * 8 + r] = bs[r];
                cand_i[(size_t)qg * 1024 + range * 8 + r] = bi[r];
            }
        }
    }
}

// ======================= final merge + outputs + logits =======================
__global__ __launch_bounds__(256) void k_merge_out(
    const float* __restrict__ cand_s, const int* __restrict__ cand_i,
    const int* __restrict__ cls, const float* __restrict__ p,
    const float* __restrict__ zn, const float* __restrict__ cn,
    float* __restrict__ out)
{
    const int tid = threadIdx.x, w = tid >> 6, lane = tid & 63;
    const int q = blockIdx.x * 4 + w;

    float ts[8]; int ti[8];
    #pragma unroll
    for (int r = 0; r < 8; ++r) { ts[r] = -FLT_MAX; ti[r] = 0x7fffffff; }
    for (int j = 0; j < 16; ++j) {
        const float sc = cand_s[(size_t)q * 1024 + j * 64 + lane];
        const int   si = cand_i[(size_t)q * 1024 + j * 64 + lane];
        float mn = ts[0]; int mni = ti[0]; int slot = 0;
        #pragma unroll
        for (int r = 1; r < 8; ++r) {
            const bool wrs = (ts[r] < mn) || ((ts[r] == mn) && (ti[r] > mni));
            if (wrs) { mn = ts[r]; mni = ti[r]; slot = r; }
        }
        const bool better = (sc > mn) || ((sc == mn) && (si < mni));
        if (better) {
            #pragma unroll
            for (int r = 0; r < 8; ++r)
                if (r == slot) { ts[r] = sc; ti[r] = si; }
        }
    }

    float tcnt = 0.f, osum = 0.f;
    #pragma unroll
    for (int r = 0; r < K_TOP; ++r) {
        float mv = ts[0]; int mi = ti[0]; int ms = 0;
        #pragma unroll
        for (int u = 1; u < 8; ++u) {
            const bool b = (ts[u] > mv) || ((ts[u] == mv) && (ti[u] < mi));
            if (b) { mv = ts[u]; mi = ti[u]; ms = u; }
        }
        float bv = mv; int bi = mi;
        #pragma unroll
        for (int m = 1; m < 64; m <<= 1) {
            const float ov = __shfl_xor(bv, m, 64);
            const int   oi = __shfl_xor(bi, m, 64);
            const bool take = (ov > bv) || ((ov == bv) && (oi < bi));
            if (take) { bv = ov; bi = oi; }
        }
        if (mv == bv && mi == bi) {
            #pragma unroll
            for (int u = 0; u < 8; ++u)
                if (u == ms) { ts[u] = -FLT_MAX; ti[u] = 0x7fffffff; }
        }
        const int cw = cls[bi];
        if (lane < C_CLS) {
            osum += p[bi * C_CLS + lane];
            tcnt += (cw == lane) ? 1.0f : 0.f;
        }
    }
    float tt = tcnt, ot = osum;
    #pragma unroll
    for (int m = 1; m < 64; m <<= 1) {
        tt += __shfl_xor(tt, m, 64);
        ot += __shfl_xor(ot, m, 64);
    }
    if (lane < C_CLS) {
        out[(size_t)B_Q * C_CLS + q * C_CLS + lane]     = tcnt / (tt + EPSF);
        out[(size_t)2 * B_Q * C_CLS + q * C_CLS + lane] = osum / (ot + EPSF);
    }

    // logits = TAU * Xn_q . cn_c  (fp32 path)
    const float* zr = zn + (size_t)q * DIM;
    float zv[8];
    #pragma unroll
    for (int i = 0; i < 8; ++i) zv[i] = zr[lane + 64 * i];
    #pragma unroll
    for (int c = 0; c < C_CLS; ++c) {
        float d = 0.f;
        #pragma unroll
        for (int i = 0; i < 8; ++i) d += zv[i] * cn[c * DIM + lane + 64 * i];
        #pragma unroll
        for (int m = 1; m < 64; m <<= 1) d += __shfl_xor(d, m, 64);
        if (lane == 0) out[q * C_CLS + c] = TAU_F * d;
    }
}

// ======================= launcher =======================
extern "C" void kernel_launch(void* const* d_in, const int* in_sizes, int n_in,
                              void* d_out, int out_size, void* d_ws, size_t ws_size,
                              hipStream_t stream)
{
    const float* z        = (const float*)d_in[0];
    const float* supports = (const float*)d_in[1];
    const float* labels   = (const float*)d_in[2];
    float* ws  = (float*)d_ws;
    float* out = (float*)d_out;

    float*     part   = ws + WS_PARTA;
    float*     pcnt   = ws + WS_PCNTA;
    float*     cn     = ws + WS_CN;
    float*     yyv    = ws + WS_YY;
    int*       cls    = (int*)(ws + WS_CLS);
    float*     p      = ws + WS_P;
    float*     zn     = ws + WS_ZN;
    float*     xx     = ws + WS_XX;
    float*     cand_s = ws + WS_CANDS;
    int*       cand_i = (int*)(ws + WS_CANDI);
    _Float16*  znh    = (_Float16*)(ws + WS_ZNH);
    _Float16*  znl    = (_Float16*)(ws + WS_ZNL);
    _Float16*  suph   = (_Float16*)(ws + WS_SUPH);
    _Float16*  supl   = (_Float16*)(ws + WS_SUPL);

    hipLaunchKernelGGL(k_centroid_accum, dim3(256), dim3(256), 0, stream,
                       supports, labels, part, pcnt);
    hipLaunchKernelGGL(k_centroid_fin, dim3(17), dim3(256), 0, stream,
                       part, pcnt, cn);
    hipLaunchKernelGGL(k_support_stats, dim3(N_S / 4), dim3(256), 0, stream,
                       supports, cn, yyv, cls, p, suph, supl);
    hipLaunchKernelGGL(k_query_norm, dim3(B_Q / 4), dim3(256), 0, stream,
                       z, zn, xx, znh, znl);
    hipLaunchKernelGGL(k_score_mfma, dim3(1024), dim3(256), 0, stream,
                       znh, znl, suph, supl, yyv, cand_s, cand_i);
    hipLaunchKernelGGL(k_merge_out, dim3(B_Q / 4), dim3(256), 0, stream,
                       cand_s, cand_i, cls, p, zn, cn, out);
}

// Round 5
// 283.794 us; speedup vs baseline: 8.4221x; 1.7709x over previous
//
#include <hip/hip_runtime.h>
#include <float.h>
#include <math.h>

// Problem constants (fixed by setup_inputs)
#define B_Q   2048
#define N_S   16384
#define DIM   512
#define C_CLS 17
#define K_TOP 8
#define TAU_F 10.0f
#define EPSF  1e-12f

typedef _Float16 f16x8 __attribute__((ext_vector_type(8)));
typedef float    f32x16 __attribute__((ext_vector_type(16)));

// ---- workspace layout (in floats) ----
// Split-f16 arrays are TILED: element (row n, k) lives at
//   [(k>>3)*NROWS + n]*8 + (k&7)  -> fragment loads are 16B/lane coalesced.
#define WS_CN     0            // 17*512
#define WS_YY     8704         // N
#define WS_CLS    25088        // N (int)
#define WS_P      41472        // N*17
#define WS_ZN     320000       // B*D fp32 (logits path)
#define WS_XX     1368576      // B (unused; kept for layout stability)
#define WS_CAND   1370624      // u64[2048][1024] = 4,194,304 floats
#define WS_ZNH    5564928      // B*D f16 tiled
#define WS_ZNL    6089216      // B*D f16 tiled
#define WS_SUPH   6613504      // N*D f16 tiled
#define WS_SUPL   10807808     // N*D f16 tiled
// total 15,002,112 floats = 60.0 MB (same footprint as round 4)
// centroid partials alias into cand region (consumed before cands exist):
#define WS_PARTA  WS_CAND                 // 256 * 8704
#define WS_PCNTA  (WS_CAND + 2228224)     // 256 * 32

// ======================= u64 sort-network helpers =======================
__device__ __forceinline__ void csd(unsigned long long& a, unsigned long long& b) {
    // descending compare-swap: a = max, b = min (branchless)
    const bool c = a > b;
    const unsigned long long mx = c ? a : b;
    const unsigned long long mn = c ? b : a;
    a = mx; b = mn;
}

__device__ __forceinline__ void sort8d(unsigned long long k[8]) {
    // Batcher odd-even, 19 comparators, descending
    csd(k[0],k[1]); csd(k[2],k[3]); csd(k[4],k[5]); csd(k[6],k[7]);
    csd(k[0],k[2]); csd(k[1],k[3]); csd(k[4],k[6]); csd(k[5],k[7]);
    csd(k[1],k[2]); csd(k[5],k[6]);
    csd(k[0],k[4]); csd(k[1],k[5]); csd(k[2],k[6]); csd(k[3],k[7]);
    csd(k[2],k[4]); csd(k[3],k[5]);
    csd(k[1],k[2]); csd(k[3],k[4]); csd(k[5],k[6]);
}

// top-8 of two sorted-descending-8 lists -> a (sorted descending)
__device__ __forceinline__ void mrg8d(unsigned long long a[8],
                                      const unsigned long long b[8]) {
    unsigned long long m[8];
    #pragma unroll
    for (int i = 0; i < 8; ++i) {
        const unsigned long long x = b[7 - i];
        m[i] = a[i] > x ? a[i] : x;
    }
    // m is bitonic (dec-then-inc); bitonic sort to descending
    csd(m[0],m[4]); csd(m[1],m[5]); csd(m[2],m[6]); csd(m[3],m[7]);
    csd(m[0],m[2]); csd(m[1],m[3]); csd(m[4],m[6]); csd(m[5],m[7]);
    csd(m[0],m[1]); csd(m[2],m[3]); csd(m[4],m[5]); csd(m[6],m[7]);
    #pragma unroll
    for (int i = 0; i < 8; ++i) a[i] = m[i];
}

__device__ __forceinline__ unsigned long long shfl_xor_u64(unsigned long long v, int m) {
    unsigned int lo = (unsigned int)v, hi = (unsigned int)(v >> 32);
    lo = __shfl_xor(lo, m, 64);
    hi = __shfl_xor(hi, m, 64);
    return ((unsigned long long)hi << 32) | lo;
}

__device__ __forceinline__ unsigned int f32_sortable(float f) {
    unsigned int u = __float_as_uint(f);
    u ^= (unsigned int)((int)u >> 31) | 0x80000000u;
    return u;
}

// ======================= centroid partial accumulation =======================
__global__ __launch_bounds__(256) void k_centroid_accum(
    const float* __restrict__ supports, const float* __restrict__ labels,
    float* __restrict__ part, float* __restrict__ pcnt)
{
    __shared__ float acc[C_CLS * DIM];
    __shared__ float lcnt[C_CLS];
    __shared__ int   lcls[64];
    const int tid = threadIdx.x;
    for (int i = tid; i < C_CLS * DIM; i += 256) acc[i] = 0.f;
    if (tid < C_CLS) lcnt[tid] = 0.f;
    __syncthreads();
    if (tid < 64) {
        const int n = blockIdx.x * 64 + tid;
        float best = labels[n * C_CLS + 0];
        int bc = 0;
        #pragma unroll
        for (int c = 1; c < C_CLS; ++c) {
            float v = labels[n * C_CLS + c];
            if (v > best) { best = v; bc = c; }
        }
        lcls[tid] = bc;
        atomicAdd(&lcnt[bc], best);   // best == 1.0 (one-hot)
    }
    __syncthreads();
    const int d0 = tid, d1 = tid + 256;
    const int base = blockIdx.x * 64;
    for (int r = 0; r < 64; ++r) {
        const int c = lcls[r];
        const float* srow = supports + (size_t)(base + r) * DIM;
        acc[c * DIM + d0] += srow[d0];
        acc[c * DIM + d1] += srow[d1];
    }
    __syncthreads();
    float* pout = part + (size_t)blockIdx.x * (C_CLS * DIM);
    for (int i = tid; i < C_CLS * DIM; i += 256) pout[i] = acc[i];
    if (tid < C_CLS) pcnt[blockIdx.x * 32 + tid] = lcnt[tid];
}

// ======================= centroid finalize (normalize) =======================
__global__ __launch_bounds__(256) void k_centroid_fin(
    const float* __restrict__ part, const float* __restrict__ pcnt,
    float* __restrict__ cn)
{
    __shared__ float red[4];
    const int c = blockIdx.x, tid = threadIdx.x;
    float cntv = 0.f;
    for (int b = 0; b < 256; ++b) cntv += pcnt[b * 32 + c];
    const float denc = cntv + EPSF;
    float v0 = 0.f, v1 = 0.f;
    for (int b = 0; b < 256; ++b) {
        const float* pb = part + (size_t)b * (C_CLS * DIM) + c * DIM;
        v0 += pb[tid];
        v1 += pb[tid + 256];
    }
    v0 /= denc;
    v1 /= denc;
    float ss = v0 * v0 + v1 * v1;
    #pragma unroll
    for (int m = 1; m < 64; m <<= 1) ss += __shfl_xor(ss, m, 64);
    if ((tid & 63) == 0) red[tid >> 6] = ss;
    __syncthreads();
    const float tot = red[0] + red[1] + red[2] + red[3];
    const float den = fmaxf(sqrtf(tot), EPSF);
    cn[c * DIM + tid]       = v0 / den;
    cn[c * DIM + 256 + tid] = v1 / den;
}

// ==== per-support: norm -> tiled f16 hi/lo, yy, temp_labels -> argmax+softmax
__global__ __launch_bounds__(256) void k_support_stats(
    const float* __restrict__ supports, const float* __restrict__ cn,
    float* __restrict__ yy, int* __restrict__ cls, float* __restrict__ p,
    _Float16* __restrict__ suph, _Float16* __restrict__ supl)
{
    __shared__ float cnl[C_CLS * DIM];
    __shared__ float ynl[4 * DIM];
    const int tid = threadIdx.x;
    for (int i = tid; i < C_CLS * DIM; i += 256) cnl[i] = cn[i];

    const int w = tid >> 6, lane = tid & 63;
    const int n = blockIdx.x * 4 + w;
    const float* srow = supports + (size_t)n * DIM;

    float s[8];
    #pragma unroll
    for (int i = 0; i < 8; ++i) s[i] = srow[lane + 64 * i];
    float ss = 0.f;
    #pragma unroll
    for (int i = 0; i < 8; ++i) ss += s[i] * s[i];
    #pragma unroll
    for (int m = 1; m < 64; m <<= 1) ss += __shfl_xor(ss, m, 64);
    const float den = fmaxf(sqrtf(ss), EPSF);

    float yn[8];
    float y2 = 0.f;
    #pragma unroll
    for (int i = 0; i < 8; ++i) {
        yn[i] = s[i] / den;
        ynl[w * DIM + lane + 64 * i] = yn[i];
        y2 += yn[i] * yn[i];
    }
    #pragma unroll
    for (int m = 1; m < 64; m <<= 1) y2 += __shfl_xor(y2, m, 64);

    __syncthreads();   // cnl + ynl ready

    float tl[C_CLS];
    #pragma unroll
    for (int c = 0; c < C_CLS; ++c) {
        float d = 0.f;
        #pragma unroll
        for (int i = 0; i < 8; ++i) d += yn[i] * cnl[c * DIM + lane + 64 * i];
        #pragma unroll
        for (int m = 1; m < 64; m <<= 1) d += __shfl_xor(d, m, 64);
        tl[c] = TAU_F * d;
    }
    float mx = tl[0];
    int am = 0;
    #pragma unroll
    for (int c = 1; c < C_CLS; ++c)
        if (tl[c] > mx) { mx = tl[c]; am = c; }
    float e[C_CLS];
    float sum = 0.f;
    #pragma unroll
    for (int c = 0; c < C_CLS; ++c) { e[c] = expf(tl[c] - mx); sum += e[c]; }

    if (lane == 0) {
        yy[n]  = y2;
        cls[n] = am;
        #pragma unroll
        for (int c = 0; c < C_CLS; ++c) p[n * C_CLS + c] = e[c] / sum;
    }

    // tiled hi/lo writes: thread t -> k-group cg = t>>2, row = t&3.
    {
        const int row = tid & 3, cg = tid >> 2;
        const float* yrow = ynl + row * DIM + cg * 8;
        f16x8 hi, lo;
        #pragma unroll
        for (int j = 0; j < 8; ++j) {
            const float v = yrow[j];
            const _Float16 hh = (_Float16)v;
            hi[j] = hh;
            lo[j] = (_Float16)(v - (float)hh);
        }
        const size_t off = ((size_t)cg * N_S + blockIdx.x * 4 + row) * 8;
        *(f16x8*)(suph + off) = hi;
        *(f16x8*)(supl + off) = lo;
    }
}

// ======================= query normalize + tiled f16 split ===================
__global__ __launch_bounds__(256) void k_query_norm(
    const float* __restrict__ z, float* __restrict__ zn,
    _Float16* __restrict__ znh, _Float16* __restrict__ znl)
{
    __shared__ float ynl[4 * DIM];
    const int tid = threadIdx.x, w = tid >> 6, lane = tid & 63;
    const int q = blockIdx.x * 4 + w;
    const float* zr = z + (size_t)q * DIM;
    float s[8];
    float ss = 0.f;
    #pragma unroll
    for (int i = 0; i < 8; ++i) { s[i] = zr[lane + 64 * i]; ss += s[i] * s[i]; }
    #pragma unroll
    for (int m = 1; m < 64; m <<= 1) ss += __shfl_xor(ss, m, 64);
    const float den = fmaxf(sqrtf(ss), EPSF);
    #pragma unroll
    for (int i = 0; i < 8; ++i) {
        const float v = s[i] / den;
        zn[(size_t)q * DIM + lane + 64 * i] = v;
        ynl[w * DIM + lane + 64 * i] = v;
    }
    __syncthreads();
    {
        const int row = tid & 3, cg = tid >> 2;
        const float* yrow = ynl + row * DIM + cg * 8;
        f16x8 hi, lo;
        #pragma unroll
        for (int j = 0; j < 8; ++j) {
            const float v = yrow[j];
            const _Float16 hh = (_Float16)v;
            hi[j] = hh;
            lo[j] = (_Float16)(v - (float)hh);
        }
        const size_t off = ((size_t)cg * B_Q + blockIdx.x * 4 + row) * 8;
        *(f16x8*)(znh + off) = hi;
        *(f16x8*)(znl + off) = lo;
    }
}

// ============ barrier-free MFMA split-f16 score GEMM + sort-net top-8 ========
// Block 128(q) x 256(s); 4 independent waves, each 64x128 (2x4 of 32x32).
// Fragments loaded DIRECTLY from the tiled global arrays (16B/lane coalesced).
// A-frags double-buffered in registers (full-chunk prefetch distance);
// B-frags reloaded right after last use. NO __syncthreads anywhere.
// Rank key: u64 = sortable(acc - 0.5*yy) << 32 | ~idx (ties -> lower idx).
#define MFMA16(a, b, c) __builtin_amdgcn_mfma_f32_32x32x16_f16(a, b, c, 0, 0, 0)

__global__ __launch_bounds__(256, 2) void k_score_mfma(
    const _Float16* __restrict__ znh, const _Float16* __restrict__ znl,
    const _Float16* __restrict__ suph, const _Float16* __restrict__ supl,
    const float* __restrict__ yy, unsigned long long* __restrict__ cand)
{
    __shared__ __align__(16) float sww[4 * 16 * 129];   // 33 KB, per-wave scratch

    const int tid = threadIdx.x;
    const int w = tid >> 6, l = tid & 63;
    const int h = l >> 5, ln = l & 31;
    const int bm = blockIdx.x & 15;
    const int bn = blockIdx.x >> 4;
    const int q0 = bm * 128, s0 = bn * 256;
    const int wm = w & 1, wn = w >> 1;

    const char* zh_c = (const char*)znh;
    const char* zl_c = (const char*)znl;
    const char* sh_c = (const char*)suph;
    const char* sl_c = (const char*)supl;

    // byte offsets into the tiled arrays (k-group g = 2c + h)
    unsigned int aoff[2], boff[4];
    #pragma unroll
    for (int t = 0; t < 2; ++t)
        aoff[t] = (unsigned int)(h * B_Q + q0 + wm * 64 + t * 32 + ln) * 16u;
    #pragma unroll
    for (int u = 0; u < 4; ++u)
        boff[u] = (unsigned int)(h * N_S + s0 + wn * 128 + u * 32 + ln) * 16u;

    f32x16 acc[2][4];
    #pragma unroll
    for (int t = 0; t < 2; ++t)
        #pragma unroll
        for (int u = 0; u < 4; ++u)
            #pragma unroll
            for (int e = 0; e < 16; ++e) acc[t][u][e] = 0.f;

    f16x8 ahb[2][2], alb[2][2], bh[4], bl[4];
    // prologue: chunk 0 fragments
    #pragma unroll
    for (int t = 0; t < 2; ++t) {
        ahb[0][t] = *(const f16x8*)(zh_c + aoff[t]);
        alb[0][t] = *(const f16x8*)(zl_c + aoff[t]);
        aoff[t] += 2u * B_Q * 16u;
    }
    #pragma unroll
    for (int u = 0; u < 4; ++u) {
        bh[u] = *(const f16x8*)(sh_c + boff[u]);
        bl[u] = *(const f16x8*)(sl_c + boff[u]);
        boff[u] += 2u * N_S * 16u;
    }

    auto do_chunk = [&](int ab, bool prefA, bool prefB) {
        if (prefA) {   // next chunk's A into the other buffer (full-chunk cover)
            #pragma unroll
            for (int t = 0; t < 2; ++t) {
                ahb[ab ^ 1][t] = *(const f16x8*)(zh_c + aoff[t]);
                alb[ab ^ 1][t] = *(const f16x8*)(zl_c + aoff[t]);
                aoff[t] += 2u * B_Q * 16u;
            }
        }
        #pragma unroll
        for (int u = 0; u < 4; ++u) {
            acc[0][u] = MFMA16(ahb[ab][0], bh[u], acc[0][u]);
            acc[1][u] = MFMA16(ahb[ab][1], bh[u], acc[1][u]);
            acc[0][u] = MFMA16(ahb[ab][0], bl[u], acc[0][u]);
            acc[1][u] = MFMA16(ahb[ab][1], bl[u], acc[1][u]);
            acc[0][u] = MFMA16(alb[ab][0], bh[u], acc[0][u]);
            acc[1][u] = MFMA16(alb[ab][1], bh[u], acc[1][u]);
            if (prefB) {
                bh[u] = *(const f16x8*)(sh_c + boff[u]);
                bl[u] = *(const f16x8*)(sl_c + boff[u]);
                boff[u] += 2u * N_S * 16u;
            }
        }
    };

    for (int cp = 0; cp < 15; ++cp) {
        do_chunk(0, true, true);
        do_chunk(1, true, true);
    }
    do_chunk(0, true, true);    // chunk 30 (prefetches chunk 31)
    do_chunk(1, false, false);  // chunk 31

    // ---------------- epilogue: per-(q,128-col range) exact top-8 -------------
    float* sw = sww + w * (16 * 129);   // per-wave scratch -> no barriers
    const int row16 = l & 15, seg = l >> 4;
    const int range = bn * 2 + wn;

    float yvh[4];
    #pragma unroll
    for (int u = 0; u < 4; ++u)
        yvh[u] = 0.5f * yy[s0 + wn * 128 + u * 32 + ln];

    #pragma unroll
    for (int pp = 0; pp < 4; ++pp) {
        const int t = pp >> 1, rb = (pp & 1) * 8;
        // transpose acc (minus 0.5*yy) into per-wave LDS
        #pragma unroll
        for (int q8 = 0; q8 < 8; ++q8) {
            const int lr = (q8 & 3) + 8 * (q8 >> 2) + 4 * h;
            #pragma unroll
            for (int u = 0; u < 4; ++u)
                sw[lr * 129 + u * 32 + ln] = acc[t][u][rb + q8] - yvh[u];
        }
        // per lane: scan 32 cols of row row16, keep sorted top-8 (u64 keys)
        const int colbase = s0 + wn * 128;
        unsigned long long A[8], G[8];
        #pragma unroll
        for (int e = 0; e < 8; ++e) {
            const int cc = seg * 32 + ((e + 8 * seg) & 31);
            const unsigned int sk = f32_sortable(sw[row16 * 129 + cc]);
            A[e] = ((unsigned long long)sk << 32) | (unsigned int)(~(colbase + cc));
        }
        sort8d(A);
        #pragma unroll
        for (int g = 1; g < 4; ++g) {
            #pragma unroll
            for (int e = 0; e < 8; ++e) {
                const int j = g * 8 + e;
                const int cc = seg * 32 + ((j + 8 * seg) & 31);
                const unsigned int sk = f32_sortable(sw[row16 * 129 + cc]);
                G[e] = ((unsigned long long)sk << 32) | (unsigned int)(~(colbase + cc));
            }
            sort8d(G);
            mrg8d(A, G);
        }
        // cross-lane merge over seg (lanes l^16, l^32)
        #pragma unroll
        for (int r = 0; r < 8; ++r) G[r] = shfl_xor_u64(A[r], 16);
        mrg8d(A, G);
        #pragma unroll
        for (int r = 0; r < 8; ++r) G[r] = shfl_xor_u64(A[r], 32);
        mrg8d(A, G);

        if (seg == 0) {
            const int qg = q0 + wm * 64 + pp * 16 + row16;
            unsigned long long* dst = cand + (size_t)qg * 1024 + range * 8;
            #pragma unroll
            for (int r = 0; r < 8; ++r) dst[r] = A[r];
        }
    }
}

// ======================= final merge + outputs + logits =======================
__global__ __launch_bounds__(256) void k_merge_out(
    const unsigned long long* __restrict__ cand,
    const int* __restrict__ cls, const float* __restrict__ p,
    const float* __restrict__ zn, const float* __restrict__ cn,
    float* __restrict__ out)
{
    const int tid = threadIdx.x, w = tid >> 6, lane = tid & 63;
    const int q = blockIdx.x * 4 + w;

    // lane-local top-8 of its 16 candidates (sorted desc)
    unsigned long long A[8], G[8];
    #pragma unroll
    for (int j = 0; j < 8; ++j) A[j] = cand[(size_t)q * 1024 + j * 64 + lane];
    sort8d(A);
    #pragma unroll
    for (int j = 0; j < 8; ++j) G[j] = cand[(size_t)q * 1024 + (j + 8) * 64 + lane];
    sort8d(G);
    mrg8d(A, G);
    // cross-lane tree merge (disjoint sets at each level)
    #pragma unroll
    for (int m = 1; m < 64; m <<= 1) {
        #pragma unroll
        for (int r = 0; r < 8; ++r) G[r] = shfl_xor_u64(A[r], m);
        mrg8d(A, G);
    }
    // all lanes now hold the exact global top-8 (desc, ties -> lower idx)
    float tcnt = 0.f, osum = 0.f;
    #pragma unroll
    for (int r = 0; r < K_TOP; ++r) {
        const int bi = (int)(~(unsigned int)A[r]) & 0xFFFF;
        const int cw = cls[bi];
        if (lane < C_CLS) {
            osum += p[bi * C_CLS + lane];
            tcnt += (cw == lane) ? 1.0f : 0.f;
        }
    }
    float tt = tcnt, ot = osum;
    #pragma unroll
    for (int m = 1; m < 64; m <<= 1) {
        tt += __shfl_xor(tt, m, 64);
        ot += __shfl_xor(ot, m, 64);
    }
    if (lane < C_CLS) {
        out[(size_t)B_Q * C_CLS + q * C_CLS + lane]     = tcnt / (tt + EPSF);
        out[(size_t)2 * B_Q * C_CLS + q * C_CLS + lane] = osum / (ot + EPSF);
    }

    // logits = TAU * Xn_q . cn_c  (fp32 path)
    const float* zr = zn + (size_t)q * DIM;
    float zv[8];
    #pragma unroll
    for (int i = 0; i < 8; ++i) zv[i] = zr[lane + 64 * i];
    #pragma unroll
    for (int c = 0; c < C_CLS; ++c) {
        float d = 0.f;
        #pragma unroll
        for (int i = 0; i < 8; ++i) d += zv[i] * cn[c * DIM + lane + 64 * i];
        #pragma unroll
        for (int m = 1; m < 64; m <<= 1) d += __shfl_xor(d, m, 64);
        if (lane == 0) out[q * C_CLS + c] = TAU_F * d;
    }
}

// ======================= launcher =======================
extern "C" void kernel_launch(void* const* d_in, const int* in_sizes, int n_in,
                              void* d_out, int out_size, void* d_ws, size_t ws_size,
                              hipStream_t stream)
{
    const float* z        = (const float*)d_in[0];
    const float* supports = (const float*)d_in[1];
    const float* labels   = (const float*)d_in[2];
    float* ws  = (float*)d_ws;
    float* out = (float*)d_out;

    float*     part   = ws + WS_PARTA;
    float*     pcnt   = ws + WS_PCNTA;
    float*     cn     = ws + WS_CN;
    float*     yyv    = ws + WS_YY;
    int*       cls    = (int*)(ws + WS_CLS);
    float*     p      = ws + WS_P;
    float*     zn     = ws + WS_ZN;
    unsigned long long* cand = (unsigned long long*)(ws + WS_CAND);
    _Float16*  znh    = (_Float16*)(ws + WS_ZNH);
    _Float16*  znl    = (_Float16*)(ws + WS_ZNL);
    _Float16*  suph   = (_Float16*)(ws + WS_SUPH);
    _Float16*  supl   = (_Float16*)(ws + WS_SUPL);

    hipLaunchKernelGGL(k_centroid_accum, dim3(256), dim3(256), 0, stream,
                       supports, labels, part, pcnt);
    hipLaunchKernelGGL(k_centroid_fin, dim3(17), dim3(256), 0, stream,
                       part, pcnt, cn);
    hipLaunchKernelGGL(k_support_stats, dim3(N_S / 4), dim3(256), 0, stream,
                       supports, cn, yyv, cls, p, suph, supl);
    hipLaunchKernelGGL(k_query_norm, dim3(B_Q / 4), dim3(256), 0, stream,
                       z, zn, znh, znl);
    hipLaunchKernelGGL(k_score_mfma, dim3(1024), dim3(256), 0, stream,
                       znh, znl, suph, supl, yyv, cand);
    hipLaunchKernelGGL(k_merge_out, dim3(B_Q / 4), dim3(256), 0, stream,
                       cand, cls, p, zn, cn, out);
}

// Round 7
// 257.577 us; speedup vs baseline: 9.2793x; 1.1018x over previous
//
#include <hip/hip_runtime.h>
#include <float.h>
#include <math.h>

// Problem constants (fixed by setup_inputs)
#define B_Q   2048
#define N_S   16384
#define DIM   512
#define C_CLS 17
#define K_TOP 8
#define TAU_F 10.0f
#define EPSF  1e-12f

typedef _Float16 f16x8 __attribute__((ext_vector_type(8)));
typedef float    f32x16 __attribute__((ext_vector_type(16)));

// ---- workspace layout (in floats) ----
// Split-f16 arrays are TILED: element (row n, k) lives at
//   [(k>>3)*NROWS + n]*8 + (k&7)  -> fragment loads are 16B/lane coalesced.
// ROUND 7 FIX: cnh/cnl are 64 groups x 32 rows x 8 f16 = 8192 floats EACH
// (round 6 allocated 4096 -> cnh/cnl/cand overlap -> wrong cls -> failure).
#define WS_CN     0            // 17*512                  -> 8704
#define WS_YY     8704         // N                       -> 25088
#define WS_CLS    25088        // N (int)                 -> 41472
#define WS_P      41472        // N*17                    -> 320000
#define WS_ZN     320000       // B*D fp32 (logits path)  -> 1368576
#define WS_CNH    1368576      // 8192 floats             -> 1376768
#define WS_CNL    1376768      // 8192 floats             -> 1384960
#define WS_CAND   1384960      // u64[2048][1024] = 4,194,304 floats -> 5579264
#define WS_ZNH    5579264      // B*D f16 tiled (524288)  -> 6103552
#define WS_ZNL    6103552      // B*D f16 tiled           -> 6627840
#define WS_SUPH   6627840      // N*D f16 tiled (4194304) -> 10822144
#define WS_SUPL   10822144     // N*D f16 tiled           -> 15016448
// total 15,016,448 floats = 60.07 MB
// centroid partials alias into cand region (consumed before cands exist):
#define WS_PARTA  WS_CAND                 // 256 * 8704
#define WS_PCNTA  (WS_CAND + 2228224)     // 256 * 32

// ======================= u64 sort-network helpers =======================
__device__ __forceinline__ void csd(unsigned long long& a, unsigned long long& b) {
    const bool c = a > b;
    const unsigned long long mx = c ? a : b;
    const unsigned long long mn = c ? b : a;
    a = mx; b = mn;
}

__device__ __forceinline__ void sort8d(unsigned long long k[8]) {
    csd(k[0],k[1]); csd(k[2],k[3]); csd(k[4],k[5]); csd(k[6],k[7]);
    csd(k[0],k[2]); csd(k[1],k[3]); csd(k[4],k[6]); csd(k[5],k[7]);
    csd(k[1],k[2]); csd(k[5],k[6]);
    csd(k[0],k[4]); csd(k[1],k[5]); csd(k[2],k[6]); csd(k[3],k[7]);
    csd(k[2],k[4]); csd(k[3],k[5]);
    csd(k[1],k[2]); csd(k[3],k[4]); csd(k[5],k[6]);
}

__device__ __forceinline__ void mrg8d(unsigned long long a[8],
                                      const unsigned long long b[8]) {
    unsigned long long m[8];
    #pragma unroll
    for (int i = 0; i < 8; ++i) {
        const unsigned long long x = b[7 - i];
        m[i] = a[i] > x ? a[i] : x;
    }
    csd(m[0],m[4]); csd(m[1],m[5]); csd(m[2],m[6]); csd(m[3],m[7]);
    csd(m[0],m[2]); csd(m[1],m[3]); csd(m[4],m[6]); csd(m[5],m[7]);
    csd(m[0],m[1]); csd(m[2],m[3]); csd(m[4],m[5]); csd(m[6],m[7]);
    #pragma unroll
    for (int i = 0; i < 8; ++i) a[i] = m[i];
}

__device__ __forceinline__ unsigned long long shfl_xor_u64(unsigned long long v, int m) {
    unsigned int lo = (unsigned int)v, hi = (unsigned int)(v >> 32);
    lo = __shfl_xor(lo, m, 64);
    hi = __shfl_xor(hi, m, 64);
    return ((unsigned long long)hi << 32) | lo;
}

__device__ __forceinline__ unsigned int f32_sortable(float f) {
    unsigned int u = __float_as_uint(f);
    u ^= (unsigned int)((int)u >> 31) | 0x80000000u;
    return u;
}

// ============ fused pre-pass: centroid partials / support & query norm+split ==
// blocks 0..255: centroid partial accumulation
// blocks 256..4351: support rows -> norm, yy, tiled f16 hi/lo
// blocks 4352..4863: query rows  -> norm, zn, tiled f16 hi/lo
__global__ __launch_bounds__(256) void k_pre(
    const float* __restrict__ z, const float* __restrict__ supports,
    const float* __restrict__ labels,
    float* __restrict__ part, float* __restrict__ pcnt,
    float* __restrict__ yy, float* __restrict__ zn,
    _Float16* __restrict__ suph, _Float16* __restrict__ supl,
    _Float16* __restrict__ znh, _Float16* __restrict__ znl)
{
    __shared__ float smem[C_CLS * DIM];   // accum scratch / ynl staging
    __shared__ float lcnt[C_CLS];
    __shared__ int   lcls[64];
    const int tid = threadIdx.x;
    const int bid = blockIdx.x;

    if (bid < 256) {
        for (int i = tid; i < C_CLS * DIM; i += 256) smem[i] = 0.f;
        if (tid < C_CLS) lcnt[tid] = 0.f;
        __syncthreads();
        if (tid < 64) {
            const int n = bid * 64 + tid;
            float best = labels[n * C_CLS + 0];
            int bc = 0;
            #pragma unroll
            for (int c = 1; c < C_CLS; ++c) {
                float v = labels[n * C_CLS + c];
                if (v > best) { best = v; bc = c; }
            }
            lcls[tid] = bc;
            atomicAdd(&lcnt[bc], best);   // best == 1.0 (one-hot)
        }
        __syncthreads();
        const int d0 = tid, d1 = tid + 256;
        const int base = bid * 64;
        for (int r = 0; r < 64; ++r) {
            const int c = lcls[r];
            const float* srow = supports + (size_t)(base + r) * DIM;
            smem[c * DIM + d0] += srow[d0];
            smem[c * DIM + d1] += srow[d1];
        }
        __syncthreads();
        float* pout = part + (size_t)bid * (C_CLS * DIM);
        for (int i = tid; i < C_CLS * DIM; i += 256) pout[i] = smem[i];
        if (tid < C_CLS) pcnt[bid * 32 + tid] = lcnt[tid];
        return;
    }

    const bool isq = (bid >= 256 + 4096);
    const int rb = isq ? (bid - 4352) : (bid - 256);
    const int w = tid >> 6, lane = tid & 63;
    const int n = rb * 4 + w;
    const float* srow = (isq ? z : supports) + (size_t)n * DIM;

    float s[8];
    float ss = 0.f;
    #pragma unroll
    for (int i = 0; i < 8; ++i) { s[i] = srow[lane + 64 * i]; ss += s[i] * s[i]; }
    #pragma unroll
    for (int m = 1; m < 64; m <<= 1) ss += __shfl_xor(ss, m, 64);
    const float den = fmaxf(sqrtf(ss), EPSF);

    float* ynl = smem;   // 4*DIM floats used
    float y2 = 0.f;
    #pragma unroll
    for (int i = 0; i < 8; ++i) {
        const float v = s[i] / den;
        ynl[w * DIM + lane + 64 * i] = v;
        y2 += v * v;
        if (isq) zn[(size_t)n * DIM + lane + 64 * i] = v;
    }
    if (!isq) {
        #pragma unroll
        for (int m = 1; m < 64; m <<= 1) y2 += __shfl_xor(y2, m, 64);
        if (lane == 0) yy[n] = y2;
    }
    __syncthreads();
    {
        const int row = tid & 3, cg = tid >> 2;
        const float* yrow = ynl + row * DIM + cg * 8;
        f16x8 hi, lo;
        #pragma unroll
        for (int j = 0; j < 8; ++j) {
            const float v = yrow[j];
            const _Float16 hh = (_Float16)v;
            hi[j] = hh;
            lo[j] = (_Float16)(v - (float)hh);
        }
        const int NR = isq ? B_Q : N_S;
        const size_t off = ((size_t)cg * NR + rb * 4 + row) * 8;
        *(f16x8*)((isq ? znh : suph) + off) = hi;
        *(f16x8*)((isq ? znl : supl) + off) = lo;
    }
}

// ============== centroid finalize: normalize + split-f16 tiled ===============
// grid 32: blocks >= 17 just zero-pad the tiled centroid rows.
__global__ __launch_bounds__(256) void k_centroid_fin(
    const float* __restrict__ part, const float* __restrict__ pcnt,
    float* __restrict__ cn, _Float16* __restrict__ cnh, _Float16* __restrict__ cnl)
{
    __shared__ float red[4];
    const int c = blockIdx.x, tid = threadIdx.x;
    if (c >= C_CLS) {
        if (tid < 64) {
            f16x8 zz = {};
            *(f16x8*)(cnh + ((size_t)tid * 32 + c) * 8) = zz;
            *(f16x8*)(cnl + ((size_t)tid * 32 + c) * 8) = zz;
        }
        return;
    }
    float cntv = 0.f;
    for (int b = 0; b < 256; ++b) cntv += pcnt[b * 32 + c];
    const float denc = cntv + EPSF;
    float v0 = 0.f, v1 = 0.f;
    for (int b = 0; b < 256; ++b) {
        const float* pb = part + (size_t)b * (C_CLS * DIM) + c * DIM;
        v0 += pb[tid];
        v1 += pb[tid + 256];
    }
    v0 /= denc;
    v1 /= denc;
    float ss = v0 * v0 + v1 * v1;
    #pragma unroll
    for (int m = 1; m < 64; m <<= 1) ss += __shfl_xor(ss, m, 64);
    if ((tid & 63) == 0) red[tid >> 6] = ss;
    __syncthreads();
    const float tot = red[0] + red[1] + red[2] + red[3];
    const float den = fmaxf(sqrtf(tot), EPSF);
    const float r0 = v0 / den, r1 = v1 / den;
    cn[c * DIM + tid]       = r0;
    cn[c * DIM + 256 + tid] = r1;
    {
        const _Float16 h0 = (_Float16)r0;
        cnh[((size_t)(tid >> 3) * 32 + c) * 8 + (tid & 7)] = h0;
        cnl[((size_t)(tid >> 3) * 32 + c) * 8 + (tid & 7)] = (_Float16)(r0 - (float)h0);
        const int d1 = tid + 256;
        const _Float16 h1 = (_Float16)r1;
        cnh[((size_t)(d1 >> 3) * 32 + c) * 8 + (d1 & 7)] = h1;
        cnl[((size_t)(d1 >> 3) * 32 + c) * 8 + (d1 & 7)] = (_Float16)(r1 - (float)h1);
    }
}

// ====== barrier-free MFMA score GEMM + sort-net top-8 (+temp_labels blocks) ==
#define MFMA16(a, b, c) __builtin_amdgcn_mfma_f32_32x32x16_f16(a, b, c, 0, 0, 0)

__global__ __launch_bounds__(256, 2) void k_score_mfma(
    const _Float16* __restrict__ znh, const _Float16* __restrict__ znl,
    const _Float16* __restrict__ suph, const _Float16* __restrict__ supl,
    const _Float16* __restrict__ cnh, const _Float16* __restrict__ cnl,
    const float* __restrict__ yy, unsigned long long* __restrict__ cand,
    int* __restrict__ cls, float* __restrict__ pout)
{
    __shared__ __align__(16) float sww[4 * 16 * 129];   // 33 KB per-wave scratch

    const int tid = threadIdx.x;
    const int w = tid >> 6, l = tid & 63;
    const int h = l >> 5, ln = l & 31;

    const char* sh_c = (const char*)suph;
    const char* sl_c = (const char*)supl;

    if (blockIdx.x >= 1024) {
        // ---- temp_labels blocks: tl = TAU*(Yn . cn), argmax + softmax ----
        const int blk = blockIdx.x - 1024;          // 0..127
        const int n0 = blk * 128 + w * 32;
        const char* ch_c = (const char*)cnh;
        const char* cl_c = (const char*)cnl;

        f32x16 acc;
        #pragma unroll
        for (int e = 0; e < 16; ++e) acc[e] = 0.f;
        for (int c = 0; c < 32; ++c) {
            const int g = 2 * c + h;
            const f16x8 ah = *(const f16x8*)(sh_c + (size_t)(g * N_S + n0 + ln) * 16);
            const f16x8 al = *(const f16x8*)(sl_c + (size_t)(g * N_S + n0 + ln) * 16);
            const f16x8 bh = *(const f16x8*)(ch_c + (size_t)(g * 32 + ln) * 16);
            const f16x8 bl = *(const f16x8*)(cl_c + (size_t)(g * 32 + ln) * 16);
            acc = MFMA16(ah, bh, acc);
            acc = MFMA16(ah, bl, acc);
            acc = MFMA16(al, bh, acc);
        }
        float* sw = sww + w * (32 * 33);
        #pragma unroll
        for (int e = 0; e < 16; ++e) {
            const int row = (e & 3) + 8 * (e >> 2) + 4 * h;
            sw[row * 33 + ln] = acc[e];
        }
        __builtin_amdgcn_s_waitcnt(0);   // drain LDS writes before cross-half read
        if (l < 32) {
            const int n = n0 + l;
            float tl[C_CLS];
            float mx = -FLT_MAX;
            int am = 0;
            #pragma unroll
            for (int c = 0; c < C_CLS; ++c) {
                tl[c] = TAU_F * sw[l * 33 + c];
                if (tl[c] > mx) { mx = tl[c]; am = c; }
            }
            float sum = 0.f;
            float e[C_CLS];
            #pragma unroll
            for (int c = 0; c < C_CLS; ++c) { e[c] = expf(tl[c] - mx); sum += e[c]; }
            cls[n] = am;
            #pragma unroll
            for (int c = 0; c < C_CLS; ++c) pout[n * C_CLS + c] = e[c] / sum;
        }
        return;
    }

    // ---- score blocks: 128(q) x 256(s), barrier-free direct-global K-loop ----
    const int bm = blockIdx.x & 15;
    const int bn = blockIdx.x >> 4;
    const int q0 = bm * 128, s0 = bn * 256;
    const int wm = w & 1, wn = w >> 1;

    const char* zh_c = (const char*)znh;
    const char* zl_c = (const char*)znl;

    unsigned int aoff[2], boff[4];
    #pragma unroll
    for (int t = 0; t < 2; ++t)
        aoff[t] = (unsigned int)(h * B_Q + q0 + wm * 64 + t * 32 + ln) * 16u;
    #pragma unroll
    for (int u = 0; u < 4; ++u)
        boff[u] = (unsigned int)(h * N_S + s0 + wn * 128 + u * 32 + ln) * 16u;

    f32x16 acc[2][4];
    #pragma unroll
    for (int t = 0; t < 2; ++t)
        #pragma unroll
        for (int u = 0; u < 4; ++u)
            #pragma unroll
            for (int e = 0; e < 16; ++e) acc[t][u][e] = 0.f;

    f16x8 ahb[2][2], alb[2][2], bh[4], bl[4];
    #pragma unroll
    for (int t = 0; t < 2; ++t) {
        ahb[0][t] = *(const f16x8*)(zh_c + aoff[t]);
        alb[0][t] = *(const f16x8*)(zl_c + aoff[t]);
        aoff[t] += 2u * B_Q * 16u;
    }
    #pragma unroll
    for (int u = 0; u < 4; ++u) {
        bh[u] = *(const f16x8*)(sh_c + boff[u]);
        bl[u] = *(const f16x8*)(sl_c + boff[u]);
        boff[u] += 2u * N_S * 16u;
    }

    auto do_chunk = [&](int ab, bool prefA, bool prefB) {
        if (prefA) {
            #pragma unroll
            for (int t = 0; t < 2; ++t) {
                ahb[ab ^ 1][t] = *(const f16x8*)(zh_c + aoff[t]);
                alb[ab ^ 1][t] = *(const f16x8*)(zl_c + aoff[t]);
                aoff[t] += 2u * B_Q * 16u;
            }
        }
        #pragma unroll
        for (int u = 0; u < 4; ++u) {
            acc[0][u] = MFMA16(ahb[ab][0], bh[u], acc[0][u]);
            acc[1][u] = MFMA16(ahb[ab][1], bh[u], acc[1][u]);
            acc[0][u] = MFMA16(ahb[ab][0], bl[u], acc[0][u]);
            acc[1][u] = MFMA16(ahb[ab][1], bl[u], acc[1][u]);
            acc[0][u] = MFMA16(alb[ab][0], bh[u], acc[0][u]);
            acc[1][u] = MFMA16(alb[ab][1], bh[u], acc[1][u]);
            if (prefB) {
                bh[u] = *(const f16x8*)(sh_c + boff[u]);
                bl[u] = *(const f16x8*)(sl_c + boff[u]);
                boff[u] += 2u * N_S * 16u;
            }
        }
    };

    for (int cp = 0; cp < 15; ++cp) {
        do_chunk(0, true, true);
        do_chunk(1, true, true);
    }
    do_chunk(0, true, true);
    do_chunk(1, false, false);

    // ---------------- epilogue: per-(q,128-col range) exact top-8 -------------
    float* sw = sww + w * (16 * 129);
    const int row16 = l & 15, seg = l >> 4;
    const int range = bn * 2 + wn;

    float yvh[4];
    #pragma unroll
    for (int u = 0; u < 4; ++u)
        yvh[u] = 0.5f * yy[s0 + wn * 128 + u * 32 + ln];

    #pragma unroll
    for (int pp = 0; pp < 4; ++pp) {
        const int t = pp >> 1, rb2 = (pp & 1) * 8;
        #pragma unroll
        for (int q8 = 0; q8 < 8; ++q8) {
            const int lr = (q8 & 3) + 8 * (q8 >> 2) + 4 * h;
            #pragma unroll
            for (int u = 0; u < 4; ++u)
                sw[lr * 129 + u * 32 + ln] = acc[t][u][rb2 + q8] - yvh[u];
        }
        const int colbase = s0 + wn * 128;
        unsigned long long A[8], G[8];
        #pragma unroll
        for (int e = 0; e < 8; ++e) {
            const int cc = seg * 32 + ((e + 8 * seg) & 31);
            const unsigned int sk = f32_sortable(sw[row16 * 129 + cc]);
            A[e] = ((unsigned long long)sk << 32) | (unsigned int)(~(colbase + cc));
        }
        sort8d(A);
        #pragma unroll
        for (int g = 1; g < 4; ++g) {
            #pragma unroll
            for (int e = 0; e < 8; ++e) {
                const int j = g * 8 + e;
                const int cc = seg * 32 + ((j + 8 * seg) & 31);
                const unsigned int sk = f32_sortable(sw[row16 * 129 + cc]);
                G[e] = ((unsigned long long)sk << 32) | (unsigned int)(~(colbase + cc));
            }
            sort8d(G);
            mrg8d(A, G);
        }
        #pragma unroll
        for (int r = 0; r < 8; ++r) G[r] = shfl_xor_u64(A[r], 16);
        mrg8d(A, G);
        #pragma unroll
        for (int r = 0; r < 8; ++r) G[r] = shfl_xor_u64(A[r], 32);
        mrg8d(A, G);

        if (seg == 0) {
            const int qg = q0 + wm * 64 + pp * 16 + row16;
            unsigned long long* dst = cand + (size_t)qg * 1024 + range * 8;
            #pragma unroll
            for (int r = 0; r < 8; ++r) dst[r] = A[r];
        }
    }
}

// ======================= final merge + outputs + logits =======================
__global__ __launch_bounds__(256) void k_merge_out(
    const unsigned long long* __restrict__ cand,
    const int* __restrict__ cls, const float* __restrict__ p,
    const float* __restrict__ zn, const float* __restrict__ cn,
    float* __restrict__ out)
{
    const int tid = threadIdx.x, w = tid >> 6, lane = tid & 63;
    const int q = blockIdx.x * 4 + w;

    unsigned long long A[8], G[8];
    #pragma unroll
    for (int j = 0; j < 8; ++j) A[j] = cand[(size_t)q * 1024 + j * 64 + lane];
    sort8d(A);
    #pragma unroll
    for (int j = 0; j < 8; ++j) G[j] = cand[(size_t)q * 1024 + (j + 8) * 64 + lane];
    sort8d(G);
    mrg8d(A, G);
    #pragma unroll
    for (int m = 1; m < 64; m <<= 1) {
        #pragma unroll
        for (int r = 0; r < 8; ++r) G[r] = shfl_xor_u64(A[r], m);
        mrg8d(A, G);
    }
    float tcnt = 0.f, osum = 0.f;
    #pragma unroll
    for (int r = 0; r < K_TOP; ++r) {
        const int bi = (int)(~(unsigned int)A[r]) & 0xFFFF;
        const int cw = cls[bi];
        if (lane < C_CLS) {
            osum += p[bi * C_CLS + lane];
            tcnt += (cw == lane) ? 1.0f : 0.f;
        }
    }
    float tt = tcnt, ot = osum;
    #pragma unroll
    for (int m = 1; m < 64; m <<= 1) {
        tt += __shfl_xor(tt, m, 64);
        ot += __shfl_xor(ot, m, 64);
    }
    if (lane < C_CLS) {
        out[(size_t)B_Q * C_CLS + q * C_CLS + lane]     = tcnt / (tt + EPSF);
        out[(size_t)2 * B_Q * C_CLS + q * C_CLS + lane] = osum / (ot + EPSF);
    }

    const float* zr = zn + (size_t)q * DIM;
    float zv[8];
    #pragma unroll
    for (int i = 0; i < 8; ++i) zv[i] = zr[lane + 64 * i];
    #pragma unroll
    for (int c = 0; c < C_CLS; ++c) {
        float d = 0.f;
        #pragma unroll
        for (int i = 0; i < 8; ++i) d += zv[i] * cn[c * DIM + lane + 64 * i];
        #pragma unroll
        for (int m = 1; m < 64; m <<= 1) d += __shfl_xor(d, m, 64);
        if (lane == 0) out[q * C_CLS + c] = TAU_F * d;
    }
}

// ======================= launcher =======================
extern "C" void kernel_launch(void* const* d_in, const int* in_sizes, int n_in,
                              void* d_out, int out_size, void* d_ws, size_t ws_size,
                              hipStream_t stream)
{
    const float* z        = (const float*)d_in[0];
    const float* supports = (const float*)d_in[1];
    const float* labels   = (const float*)d_in[2];
    float* ws  = (float*)d_ws;
    float* out = (float*)d_out;

    float*     part   = ws + WS_PARTA;
    float*     pcnt   = ws + WS_PCNTA;
    float*     cn     = ws + WS_CN;
    float*     yyv    = ws + WS_YY;
    int*       cls    = (int*)(ws + WS_CLS);
    float*     p      = ws + WS_P;
    float*     zn     = ws + WS_ZN;
    unsigned long long* cand = (unsigned long long*)(ws + WS_CAND);
    _Float16*  cnh    = (_Float16*)(ws + WS_CNH);
    _Float16*  cnl    = (_Float16*)(ws + WS_CNL);
    _Float16*  znh    = (_Float16*)(ws + WS_ZNH);
    _Float16*  znl    = (_Float16*)(ws + WS_ZNL);
    _Float16*  suph   = (_Float16*)(ws + WS_SUPH);
    _Float16*  supl   = (_Float16*)(ws + WS_SUPL);

    hipLaunchKernelGGL(k_pre, dim3(4864), dim3(256), 0, stream,
                       z, supports, labels, part, pcnt, yyv, zn,
                       suph, supl, znh, znl);
    hipLaunchKernelGGL(k_centroid_fin, dim3(32), dim3(256), 0, stream,
                       part, pcnt, cn, cnh, cnl);
    hipLaunchKernelGGL(k_score_mfma, dim3(1152), dim3(256), 0, stream,
                       znh, znl, suph, supl, cnh, cnl, yyv, cand, cls, p);
    hipLaunchKernelGGL(k_merge_out, dim3(512), dim3(256), 0, stream,
                       cand, cls, p, zn, cn, out);
}

// Round 8
// 238.270 us; speedup vs baseline: 10.0312x; 1.0810x over previous
//
#include <hip/hip_runtime.h>
#include <float.h>
#include <math.h>

// Problem constants (fixed by setup_inputs)
#define B_Q   2048
#define N_S   16384
#define DIM   512
#define C_CLS 17
#define K_TOP 8
#define TAU_F 10.0f
#define EPSF  1e-12f

typedef _Float16 f16x8 __attribute__((ext_vector_type(8)));
typedef float    f32x16 __attribute__((ext_vector_type(16)));

// ---- workspace layout (in floats) ----
// Split-f16 arrays are TILED: element (row n, k) lives at
//   [(k>>3)*NROWS + n]*8 + (k&7)  -> fragment loads are 16B/lane coalesced.
#define WS_YY     0            // N                        -> 16384
#define WS_CLS    16384        // N (int)                  -> 32768
#define WS_P      32768        // N*17                     -> 311296
#define WS_CNH    311296       // 64*32*8 f16 = 8192 fl    -> 319488
#define WS_CNL    319488       // 8192 fl                  -> 327680
#define WS_CAND   327680       // u64[2048][1024]          -> 4521984
#define WS_ZNH    4521984      // B*D f16 tiled (524288)   -> 5046272
#define WS_ZNL    5046272      //                          -> 5570560
#define WS_SUPH   5570560      // N*D f16 tiled (4194304)  -> 9764864
#define WS_SUPL   9764864      //                          -> 13959168
// total 13,959,168 floats = 55.8 MB
// centroid partials alias into cand region (consumed before cands exist):
#define WS_PARTA  WS_CAND                 // 256 * 8704 = 2228224
#define WS_PCNTA  (WS_CAND + 2228224)     // 256 * 32

// ======================= u64 sort-network helpers =======================
__device__ __forceinline__ void csd(unsigned long long& a, unsigned long long& b) {
    const bool c = a > b;
    const unsigned long long mx = c ? a : b;
    const unsigned long long mn = c ? b : a;
    a = mx; b = mn;
}

__device__ __forceinline__ void sort8d(unsigned long long k[8]) {
    csd(k[0],k[1]); csd(k[2],k[3]); csd(k[4],k[5]); csd(k[6],k[7]);
    csd(k[0],k[2]); csd(k[1],k[3]); csd(k[4],k[6]); csd(k[5],k[7]);
    csd(k[1],k[2]); csd(k[5],k[6]);
    csd(k[0],k[4]); csd(k[1],k[5]); csd(k[2],k[6]); csd(k[3],k[7]);
    csd(k[2],k[4]); csd(k[3],k[5]);
    csd(k[1],k[2]); csd(k[3],k[4]); csd(k[5],k[6]);
}

__device__ __forceinline__ void mrg8d(unsigned long long a[8],
                                      const unsigned long long b[8]) {
    unsigned long long m[8];
    #pragma unroll
    for (int i = 0; i < 8; ++i) {
        const unsigned long long x = b[7 - i];
        m[i] = a[i] > x ? a[i] : x;
    }
    csd(m[0],m[4]); csd(m[1],m[5]); csd(m[2],m[6]); csd(m[3],m[7]);
    csd(m[0],m[2]); csd(m[1],m[3]); csd(m[4],m[6]); csd(m[5],m[7]);
    csd(m[0],m[1]); csd(m[2],m[3]); csd(m[4],m[5]); csd(m[6],m[7]);
    #pragma unroll
    for (int i = 0; i < 8; ++i) a[i] = m[i];
}

__device__ __forceinline__ unsigned long long shfl_xor_u64(unsigned long long v, int m) {
    unsigned int lo = (unsigned int)v, hi = (unsigned int)(v >> 32);
    lo = __shfl_xor(lo, m, 64);
    hi = __shfl_xor(hi, m, 64);
    return ((unsigned long long)hi << 32) | lo;
}

__device__ __forceinline__ unsigned int f32_sortable(float f) {
    unsigned int u = __float_as_uint(f);
    u ^= (unsigned int)((int)u >> 31) | 0x80000000u;
    return u;
}

// ============ fused pre-pass: centroid partials / support & query norm+split ==
// blocks 0..255: centroid partial accumulation
// blocks 256..4351: support rows -> norm, yy, tiled f16 hi/lo
// blocks 4352..4863: query rows  -> norm, tiled f16 hi/lo
__global__ __launch_bounds__(256) void k_pre(
    const float* __restrict__ z, const float* __restrict__ supports,
    const float* __restrict__ labels,
    float* __restrict__ part, float* __restrict__ pcnt,
    float* __restrict__ yy,
    _Float16* __restrict__ suph, _Float16* __restrict__ supl,
    _Float16* __restrict__ znh, _Float16* __restrict__ znl)
{
    __shared__ float smem[C_CLS * DIM];   // accum scratch / ynl staging
    __shared__ float lcnt[C_CLS];
    __shared__ int   lcls[64];
    const int tid = threadIdx.x;
    const int bid = blockIdx.x;

    if (bid < 256) {
        for (int i = tid; i < C_CLS * DIM; i += 256) smem[i] = 0.f;
        if (tid < C_CLS) lcnt[tid] = 0.f;
        __syncthreads();
        if (tid < 64) {
            const int n = bid * 64 + tid;
            float best = labels[n * C_CLS + 0];
            int bc = 0;
            #pragma unroll
            for (int c = 1; c < C_CLS; ++c) {
                float v = labels[n * C_CLS + c];
                if (v > best) { best = v; bc = c; }
            }
            lcls[tid] = bc;
            atomicAdd(&lcnt[bc], best);   // best == 1.0 (one-hot)
        }
        __syncthreads();
        const int d0 = tid, d1 = tid + 256;
        const int base = bid * 64;
        for (int r = 0; r < 64; ++r) {
            const int c = lcls[r];
            const float* srow = supports + (size_t)(base + r) * DIM;
            smem[c * DIM + d0] += srow[d0];
            smem[c * DIM + d1] += srow[d1];
        }
        __syncthreads();
        float* pout = part + (size_t)bid * (C_CLS * DIM);
        for (int i = tid; i < C_CLS * DIM; i += 256) pout[i] = smem[i];
        if (tid < C_CLS) pcnt[bid * 32 + tid] = lcnt[tid];
        return;
    }

    const bool isq = (bid >= 256 + 4096);
    const int rb = isq ? (bid - 4352) : (bid - 256);
    const int w = tid >> 6, lane = tid & 63;
    const int n = rb * 4 + w;
    const float* srow = (isq ? z : supports) + (size_t)n * DIM;

    float s[8];
    float ss = 0.f;
    #pragma unroll
    for (int i = 0; i < 8; ++i) { s[i] = srow[lane + 64 * i]; ss += s[i] * s[i]; }
    #pragma unroll
    for (int m = 1; m < 64; m <<= 1) ss += __shfl_xor(ss, m, 64);
    const float den = fmaxf(sqrtf(ss), EPSF);

    float* ynl = smem;   // 4*DIM floats used
    float y2 = 0.f;
    #pragma unroll
    for (int i = 0; i < 8; ++i) {
        const float v = s[i] / den;
        ynl[w * DIM + lane + 64 * i] = v;
        y2 += v * v;
    }
    if (!isq) {
        #pragma unroll
        for (int m = 1; m < 64; m <<= 1) y2 += __shfl_xor(y2, m, 64);
        if (lane == 0) yy[n] = y2;
    }
    __syncthreads();
    {
        const int row = tid & 3, cg = tid >> 2;
        const float* yrow = ynl + row * DIM + cg * 8;
        f16x8 hi, lo;
        #pragma unroll
        for (int j = 0; j < 8; ++j) {
            const float v = yrow[j];
            const _Float16 hh = (_Float16)v;
            hi[j] = hh;
            lo[j] = (_Float16)(v - (float)hh);
        }
        const int NR = isq ? B_Q : N_S;
        const size_t off = ((size_t)cg * NR + rb * 4 + row) * 8;
        *(f16x8*)((isq ? znh : suph) + off) = hi;
        *(f16x8*)((isq ? znl : supl) + off) = lo;
    }
}

// ============== centroid finalize: normalize + split-f16 tiled ===============
// grid 32: blocks >= 17 just zero-pad the tiled centroid rows.
__global__ __launch_bounds__(256) void k_centroid_fin(
    const float* __restrict__ part, const float* __restrict__ pcnt,
    _Float16* __restrict__ cnh, _Float16* __restrict__ cnl)
{
    __shared__ float red[4];
    const int c = blockIdx.x, tid = threadIdx.x;
    if (c >= C_CLS) {
        if (tid < 64) {
            f16x8 zz = {};
            *(f16x8*)(cnh + ((size_t)tid * 32 + c) * 8) = zz;
            *(f16x8*)(cnl + ((size_t)tid * 32 + c) * 8) = zz;
        }
        return;
    }
    float cntv = 0.f;
    for (int b = 0; b < 256; ++b) cntv += pcnt[b * 32 + c];
    const float denc = cntv + EPSF;
    float v0 = 0.f, v1 = 0.f;
    for (int b = 0; b < 256; ++b) {
        const float* pb = part + (size_t)b * (C_CLS * DIM) + c * DIM;
        v0 += pb[tid];
        v1 += pb[tid + 256];
    }
    v0 /= denc;
    v1 /= denc;
    float ss = v0 * v0 + v1 * v1;
    #pragma unroll
    for (int m = 1; m < 64; m <<= 1) ss += __shfl_xor(ss, m, 64);
    if ((tid & 63) == 0) red[tid >> 6] = ss;
    __syncthreads();
    const float tot = red[0] + red[1] + red[2] + red[3];
    const float den = fmaxf(sqrtf(tot), EPSF);
    const float r0 = v0 / den, r1 = v1 / den;
    {
        const _Float16 h0 = (_Float16)r0;
        cnh[((size_t)(tid >> 3) * 32 + c) * 8 + (tid & 7)] = h0;
        cnl[((size_t)(tid >> 3) * 32 + c) * 8 + (tid & 7)] = (_Float16)(r0 - (float)h0);
        const int d1 = tid + 256;
        const _Float16 h1 = (_Float16)r1;
        cnh[((size_t)(d1 >> 3) * 32 + c) * 8 + (d1 & 7)] = h1;
        cnl[((size_t)(d1 >> 3) * 32 + c) * 8 + (d1 & 7)] = (_Float16)(r1 - (float)h1);
    }
}

// ====== MFMA score GEMM + sort-net top-8 (+temp_labels & query-logits) =======
// blocks 0..127:   temp_labels (tl = TAU*(Yn.cn) -> argmax cls + softmax p)
// blocks 128..143: query logits (TAU*(Zn.cn) -> out[0..B*C))
// blocks 144..1167: score blocks, XCD-swizzled: xcd = local&7 owns bn range
//   [8*xcd, 8*xcd+8) so each XCD's B working set (4 MB) fits its L2.
#define MFMA16(a, b, c) __builtin_amdgcn_mfma_f32_32x32x16_f16(a, b, c, 0, 0, 0)

__global__ __launch_bounds__(256, 2) void k_score_mfma(
    const _Float16* __restrict__ znh, const _Float16* __restrict__ znl,
    const _Float16* __restrict__ suph, const _Float16* __restrict__ supl,
    const _Float16* __restrict__ cnh, const _Float16* __restrict__ cnl,
    const float* __restrict__ yy, unsigned long long* __restrict__ cand,
    int* __restrict__ cls, float* __restrict__ pout, float* __restrict__ out)
{
    __shared__ __align__(16) float sww[4 * 16 * 129];   // 33 KB per-wave scratch

    const int tid = threadIdx.x;
    const int w = tid >> 6, l = tid & 63;
    const int h = l >> 5, ln = l & 31;
    const int blk = (int)blockIdx.x;

    const char* sh_c = (const char*)suph;
    const char* sl_c = (const char*)supl;

    if (blk < 144) {
        // ---- tl / ql blocks: 128-row GEMM vs centroids, double-buffered ----
        const bool isq = (blk >= 128);
        const int b2 = isq ? blk - 128 : blk;
        const int NR = isq ? B_Q : N_S;
        const char* rh_c = isq ? (const char*)znh : sh_c;
        const char* rl_c = isq ? (const char*)znl : sl_c;
        const char* ch_c = (const char*)cnh;
        const char* cl_c = (const char*)cnl;
        const int n0 = b2 * 128 + w * 32;

        f32x16 acc;
        #pragma unroll
        for (int e = 0; e < 16; ++e) acc[e] = 0.f;

        f16x8 ah[2], al[2], bh2[2], bl2[2];
        {
            const int g = h;
            ah[0]  = *(const f16x8*)(rh_c + (size_t)(g * NR + n0 + ln) * 16);
            al[0]  = *(const f16x8*)(rl_c + (size_t)(g * NR + n0 + ln) * 16);
            bh2[0] = *(const f16x8*)(ch_c + (size_t)(g * 32 + ln) * 16);
            bl2[0] = *(const f16x8*)(cl_c + (size_t)(g * 32 + ln) * 16);
        }
        for (int c = 0; c < 32; ++c) {
            const int cur = c & 1;
            if (c + 1 < 32) {
                const int g = 2 * (c + 1) + h;
                ah[cur ^ 1]  = *(const f16x8*)(rh_c + (size_t)(g * NR + n0 + ln) * 16);
                al[cur ^ 1]  = *(const f16x8*)(rl_c + (size_t)(g * NR + n0 + ln) * 16);
                bh2[cur ^ 1] = *(const f16x8*)(ch_c + (size_t)(g * 32 + ln) * 16);
                bl2[cur ^ 1] = *(const f16x8*)(cl_c + (size_t)(g * 32 + ln) * 16);
            }
            acc = MFMA16(ah[cur], bh2[cur], acc);
            acc = MFMA16(ah[cur], bl2[cur], acc);
            acc = MFMA16(al[cur], bh2[cur], acc);
        }
        float* sw = sww + w * (32 * 33);
        #pragma unroll
        for (int e = 0; e < 16; ++e) {
            const int row = (e & 3) + 8 * (e >> 2) + 4 * h;
            sw[row * 33 + ln] = acc[e];
        }
        __builtin_amdgcn_s_waitcnt(0);   // drain LDS writes before cross-half read
        if (l < 32) {
            const int n = n0 + l;
            if (isq) {
                #pragma unroll
                for (int c = 0; c < C_CLS; ++c)
                    out[n * C_CLS + c] = TAU_F * sw[l * 33 + c];
            } else {
                float tl[C_CLS];
                float mx = -FLT_MAX;
                int am = 0;
                #pragma unroll
                for (int c = 0; c < C_CLS; ++c) {
                    tl[c] = TAU_F * sw[l * 33 + c];
                    if (tl[c] > mx) { mx = tl[c]; am = c; }
                }
                float sum = 0.f;
                float e[C_CLS];
                #pragma unroll
                for (int c = 0; c < C_CLS; ++c) { e[c] = expf(tl[c] - mx); sum += e[c]; }
                cls[n] = am;
                #pragma unroll
                for (int c = 0; c < C_CLS; ++c) pout[n * C_CLS + c] = e[c] / sum;
            }
        }
        return;
    }

    // ---- score blocks: 128(q) x 256(s), barrier-free direct-global K-loop ----
    const int local = blk - 144;
    const int xcd = local & 7, sseq = local >> 3;
    const int bn = (xcd << 3) | (sseq >> 4);
    const int bm = sseq & 15;
    const int q0 = bm * 128, s0 = bn * 256;
    const int wm = w & 1, wn = w >> 1;

    const char* zh_c = (const char*)znh;
    const char* zl_c = (const char*)znl;

    unsigned int aoff[2], boff[4];
    #pragma unroll
    for (int t = 0; t < 2; ++t)
        aoff[t] = (unsigned int)(h * B_Q + q0 + wm * 64 + t * 32 + ln) * 16u;
    #pragma unroll
    for (int u = 0; u < 4; ++u)
        boff[u] = (unsigned int)(h * N_S + s0 + wn * 128 + u * 32 + ln) * 16u;

    f32x16 acc[2][4];
    #pragma unroll
    for (int t = 0; t < 2; ++t)
        #pragma unroll
        for (int u = 0; u < 4; ++u)
            #pragma unroll
            for (int e = 0; e < 16; ++e) acc[t][u][e] = 0.f;

    f16x8 ahb[2][2], alb[2][2], bh[4], bl[4];
    #pragma unroll
    for (int t = 0; t < 2; ++t) {
        ahb[0][t] = *(const f16x8*)(zh_c + aoff[t]);
        alb[0][t] = *(const f16x8*)(zl_c + aoff[t]);
        aoff[t] += 2u * B_Q * 16u;
    }
    #pragma unroll
    for (int u = 0; u < 4; ++u) {
        bh[u] = *(const f16x8*)(sh_c + boff[u]);
        bl[u] = *(const f16x8*)(sl_c + boff[u]);
        boff[u] += 2u * N_S * 16u;
    }

    auto do_chunk = [&](int ab, bool prefA, bool prefB) {
        if (prefA) {
            #pragma unroll
            for (int t = 0; t < 2; ++t) {
                ahb[ab ^ 1][t] = *(const f16x8*)(zh_c + aoff[t]);
                alb[ab ^ 1][t] = *(const f16x8*)(zl_c + aoff[t]);
                aoff[t] += 2u * B_Q * 16u;
            }
        }
        #pragma unroll
        for (int u = 0; u < 4; ++u) {
            acc[0][u] = MFMA16(ahb[ab][0], bh[u], acc[0][u]);
            acc[1][u] = MFMA16(ahb[ab][1], bh[u], acc[1][u]);
            acc[0][u] = MFMA16(ahb[ab][0], bl[u], acc[0][u]);
            acc[1][u] = MFMA16(ahb[ab][1], bl[u], acc[1][u]);
            acc[0][u] = MFMA16(alb[ab][0], bh[u], acc[0][u]);
            acc[1][u] = MFMA16(alb[ab][1], bh[u], acc[1][u]);
            if (prefB) {
                bh[u] = *(const f16x8*)(sh_c + boff[u]);
                bl[u] = *(const f16x8*)(sl_c + boff[u]);
                boff[u] += 2u * N_S * 16u;
            }
        }
    };

    for (int cp = 0; cp < 15; ++cp) {
        do_chunk(0, true, true);
        do_chunk(1, true, true);
    }
    do_chunk(0, true, true);
    do_chunk(1, false, false);

    // ---------------- epilogue: per-(q,128-col range) exact top-8 -------------
    float* sw = sww + w * (16 * 129);
    const int row16 = l & 15, seg = l >> 4;
    const int range = bn * 2 + wn;

    float yvh[4];
    #pragma unroll
    for (int u = 0; u < 4; ++u)
        yvh[u] = 0.5f * yy[s0 + wn * 128 + u * 32 + ln];

    #pragma unroll
    for (int pp = 0; pp < 4; ++pp) {
        const int t = pp >> 1, rb2 = (pp & 1) * 8;
        #pragma unroll
        for (int q8 = 0; q8 < 8; ++q8) {
            const int lr = (q8 & 3) + 8 * (q8 >> 2) + 4 * h;
            #pragma unroll
            for (int u = 0; u < 4; ++u)
                sw[lr * 129 + u * 32 + ln] = acc[t][u][rb2 + q8] - yvh[u];
        }
        const int colbase = s0 + wn * 128;
        unsigned long long A[8], G[8];
        #pragma unroll
        for (int e = 0; e < 8; ++e) {
            const int cc = seg * 32 + ((e + 8 * seg) & 31);
            const unsigned int sk = f32_sortable(sw[row16 * 129 + cc]);
            A[e] = ((unsigned long long)sk << 32) | (unsigned int)(~(colbase + cc));
        }
        sort8d(A);
        #pragma unroll
        for (int g = 1; g < 4; ++g) {
            #pragma unroll
            for (int e = 0; e < 8; ++e) {
                const int j = g * 8 + e;
                const int cc = seg * 32 + ((j + 8 * seg) & 31);
                const unsigned int sk = f32_sortable(sw[row16 * 129 + cc]);
                G[e] = ((unsigned long long)sk << 32) | (unsigned int)(~(colbase + cc));
            }
            sort8d(G);
            mrg8d(A, G);
        }
        #pragma unroll
        for (int r = 0; r < 8; ++r) G[r] = shfl_xor_u64(A[r], 16);
        mrg8d(A, G);
        #pragma unroll
        for (int r = 0; r < 8; ++r) G[r] = shfl_xor_u64(A[r], 32);
        mrg8d(A, G);

        if (seg == 0) {
            const int qg = q0 + wm * 64 + pp * 16 + row16;
            unsigned long long* dst = cand + (size_t)qg * 1024 + range * 8;
            #pragma unroll
            for (int r = 0; r < 8; ++r) dst[r] = A[r];
        }
    }
}

// ======================= final merge + targets/outputs =======================
__global__ __launch_bounds__(256) void k_merge_out(
    const unsigned long long* __restrict__ cand,
    const int* __restrict__ cls, const float* __restrict__ p,
    float* __restrict__ out)
{
    const int tid = threadIdx.x, w = tid >> 6, lane = tid & 63;
    const int q = blockIdx.x * 4 + w;

    unsigned long long A[8], G[8];
    #pragma unroll
    for (int j = 0; j < 8; ++j) A[j] = cand[(size_t)q * 1024 + j * 64 + lane];
    sort8d(A);
    #pragma unroll
    for (int j = 0; j < 8; ++j) G[j] = cand[(size_t)q * 1024 + (j + 8) * 64 + lane];
    sort8d(G);
    mrg8d(A, G);
    #pragma unroll
    for (int m = 1; m < 64; m <<= 1) {
        #pragma unroll
        for (int r = 0; r < 8; ++r) G[r] = shfl_xor_u64(A[r], m);
        mrg8d(A, G);
    }
    float tcnt = 0.f, osum = 0.f;
    #pragma unroll
    for (int r = 0; r < K_TOP; ++r) {
        const int bi = (int)(~(unsigned int)A[r]) & 0xFFFF;
        const int cw = cls[bi];
        if (lane < C_CLS) {
            osum += p[bi * C_CLS + lane];
            tcnt += (cw == lane) ? 1.0f : 0.f;
        }
    }
    float tt = tcnt, ot = osum;
    #pragma unroll
    for (int m = 1; m < 64; m <<= 1) {
        tt += __shfl_xor(tt, m, 64);
        ot += __shfl_xor(ot, m, 64);
    }
    if (lane < C_CLS) {
        out[(size_t)B_Q * C_CLS + q * C_CLS + lane]     = tcnt / (tt + EPSF);
        out[(size_t)2 * B_Q * C_CLS + q * C_CLS + lane] = osum / (ot + EPSF);
    }
}

// ======================= launcher =======================
extern "C" void kernel_launch(void* const* d_in, const int* in_sizes, int n_in,
                              void* d_out, int out_size, void* d_ws, size_t ws_size,
                              hipStream_t stream)
{
    const float* z        = (const float*)d_in[0];
    const float* supports = (const float*)d_in[1];
    const float* labels   = (const float*)d_in[2];
    float* ws  = (float*)d_ws;
    float* out = (float*)d_out;

    float*     part   = ws + WS_PARTA;
    float*     pcnt   = ws + WS_PCNTA;
    float*     yyv    = ws + WS_YY;
    int*       cls    = (int*)(ws + WS_CLS);
    float*     p      = ws + WS_P;
    unsigned long long* cand = (unsigned long long*)(ws + WS_CAND);
    _Float16*  cnh    = (_Float16*)(ws + WS_CNH);
    _Float16*  cnl    = (_Float16*)(ws + WS_CNL);
    _Float16*  znh    = (_Float16*)(ws + WS_ZNH);
    _Float16*  znl    = (_Float16*)(ws + WS_ZNL);
    _Float16*  suph   = (_Float16*)(ws + WS_SUPH);
    _Float16*  supl   = (_Float16*)(ws + WS_SUPL);

    hipLaunchKernelGGL(k_pre, dim3(4864), dim3(256), 0, stream,
                       z, supports, labels, part, pcnt, yyv,
                       suph, supl, znh, znl);
    hipLaunchKernelGGL(k_centroid_fin, dim3(32), dim3(256), 0, stream,
                       part, pcnt, cnh, cnl);
    hipLaunchKernelGGL(k_score_mfma, dim3(1168), dim3(256), 0, stream,
                       znh, znl, suph, supl, cnh, cnl, yyv, cand, cls, p, out);
    hipLaunchKernelGGL(k_merge_out, dim3(512), dim3(256), 0, stream,
                       cand, cls, p, out);
}